// Round 6
// baseline (4366.653 us; speedup 1.0000x reference)
//
#include <hip/hip_runtime.h>
#include <math.h>

#define LL 16
#define WD 256
#define G3 768

// ws layout (u32 units)
#define OFF_AR3 0        // 57344 u32 : A f16 pairs, reg part (28 uint4/thread)
#define OFF_AL3 57344    // 8192 u32  : A f16 pairs, LDS part (4 uint4/thread)
#define OFF_B8  65536    // 49152 u32 : W_hh int8 (24 uint4/thread)
#define OFF_SR  114688   // 768 f32 : per-row scale of W_hh
#define OFF_GA  115456   // 768 f32 : W_ih[:,0]-W_ih[:,1]
#define OFF_GBI 116224   // 768 f32 : W_ih[:,1]+b_ih

typedef _Float16 h2v __attribute__((ext_vector_type(2)));

__device__ __forceinline__ unsigned packh2(float a, float b) {
    h2v v; v.x = (_Float16)a; v.y = (_Float16)b;
    return __builtin_bit_cast(unsigned, v);
}
__device__ __forceinline__ float dot2f(unsigned w, unsigned h, float acc) {
#if __has_builtin(__builtin_amdgcn_fdot2)
    return __builtin_amdgcn_fdot2(__builtin_bit_cast(h2v, w),
                                  __builtin_bit_cast(h2v, h), acc, false);
#else
    h2v a = __builtin_bit_cast(h2v, w), b = __builtin_bit_cast(h2v, h);
    return acc + (float)a.x * (float)b.x + (float)a.y * (float)b.y;
#endif
}
__device__ __forceinline__ int sdot4(unsigned a, unsigned b, int acc) {
#if __has_builtin(__builtin_amdgcn_sdot4)
    return __builtin_amdgcn_sdot4((int)a, (int)b, acc, false);
#else
    int s = acc;
    #pragma unroll
    for (int r = 0; r < 4; ++r)
        s += (int)(signed char)(a >> (8 * r)) * (int)(signed char)(b >> (8 * r));
    return s;
#endif
}
__device__ __forceinline__ unsigned short f16b(float v) {
    _Float16 h = (_Float16)v; return __builtin_bit_cast(unsigned short, h);
}
__device__ __forceinline__ float fsig(float v) { return 1.f / (1.f + __expf(-v)); }
__device__ __forceinline__ float ftanh_(float v) {
    v = fminf(fmaxf(v, -15.f), 15.f);
    float e = __expf(-2.f * v);
    return (1.f - e) / (1.f + e);
}
__device__ __forceinline__ int clampi8(int q) {
    return q > 127 ? 127 : (q < -127 ? -127 : q);
}

// per-row max-abs of W_hh -> scale
__global__ __launch_bounds__(64)
void gru2d_prep1(const float* __restrict__ W_hh, float* __restrict__ ws) {
    int row = blockIdx.x, lane = threadIdx.x;
    float s = 0.f;
    for (int k = lane; k < 256; k += 64) s = fmaxf(s, fabsf(W_hh[row * 256 + k]));
    #pragma unroll
    for (int o = 32; o > 0; o >>= 1) s = fmaxf(s, __shfl_down(s, o));
    if (lane == 0) ws[OFF_SR + row] = (s > 0.f) ? s * (1.f / 127.f) : 1.f;
}

// Main-kernel thread t: v=t>>6 (wave), l=t&63.
// Phase A role: chA=v>>2, baseA=(v&3)*64, rows r0=baseA+(l&31), r1=r0+32,
//   k-quarter koff = chA*256 + (l>>5)*128 (concat-k of [Wh_l|Wh_u]).
//   Per row 64 u32 of f16-pairs: jj<56 in regs (wAr[row*56+jj]), jj>=56 in LDS.
// Phase B role: wB=v*32+(l&31), chB=l>>5; gate rows {wB,256+wB,512+wB},
//   k in [chB*128,+128) as i8: wB8[gate*32+q], q=u32 index.
__global__ __launch_bounds__(256)
void gru2d_prep2(const float* __restrict__ W_ih, const float* __restrict__ W_hh,
                 const float* __restrict__ b_ih, const float* __restrict__ W_hcat,
                 float* __restrict__ ws) {
    unsigned* __restrict__ wsu = (unsigned*)ws;
    int m = blockIdx.x * 256 + threadIdx.x;
    if (m < 57344) {
        int g = m >> 11, t = (m >> 2) & 511, rr = m & 3;
        int jl = g * 4 + rr;
        int rs = (jl >= 56) ? 1 : 0;
        int jj = jl - 56 * rs;
        int v = t >> 6, l = t & 63;
        int chA = v >> 2, baseA = (v & 3) * 64;
        int r = baseA + (l & 31) + 32 * rs;
        int koff = chA * 256 + (l >> 5) * 128;
        int pb = r * 512 + koff + 2 * jj;
        wsu[OFF_AR3 + m] = packh2(W_hcat[pb], W_hcat[pb + 1]);
    } else if (m < 65536) {
        int mm = m - 57344;
        int g = mm >> 11, t = (mm >> 2) & 511, rr = mm & 3;
        int rs = g >> 1;
        int jj = 56 + (g & 1) * 4 + rr;
        int v = t >> 6, l = t & 63;
        int chA = v >> 2, baseA = (v & 3) * 64;
        int r = baseA + (l & 31) + 32 * rs;
        int koff = chA * 256 + (l >> 5) * 128;
        int pb = r * 512 + koff + 2 * jj;
        wsu[OFF_AL3 + mm] = packh2(W_hcat[pb], W_hcat[pb + 1]);
    } else if (m < 114688) {
        int mm = m - 65536;
        int g4 = mm >> 11, t = (mm >> 2) & 511, rr = mm & 3;
        int ql = g4 * 4 + rr;
        int gate = ql >> 5, q = ql & 31;
        int v = t >> 6, l = t & 63;
        int wB_ = v * 32 + (l & 31), chB = l >> 5;
        int row = gate * 256 + wB_;
        float inv = 1.f / ws[OFF_SR + row];
        int kb = row * 256 + chB * 128 + 4 * q;
        unsigned pk = 0;
        #pragma unroll
        for (int bb = 0; bb < 4; ++bb) {
            int qv = clampi8(__float2int_rn(W_hh[kb + bb] * inv));
            pk |= ((unsigned)(qv & 255)) << (8 * bb);
        }
        wsu[OFF_B8 + mm] = pk;
    } else if (m < 115456) {
        int e = m - 114688;
        float w0 = W_ih[2 * e], w1 = W_ih[2 * e + 1];
        ws[OFF_GA + e] = w0 - w1;
        ws[OFF_GBI + e] = w1 + b_ih[e];
    }
}

// 512 threads (2 waves/SIMD, 256-reg pool), 1 block/CU, 2 batches/block.
// 3 barriers/step; all cross-k reductions via shfl_xor(32); weights persistent.
__global__ __launch_bounds__(512, 2)
void gru2d_main(const float* __restrict__ x, const float* __restrict__ b_hh,
                const float* __restrict__ W_fc, const float* __restrict__ b_fc,
                const float* __restrict__ W_xcat, const float* __restrict__ ws,
                float* __restrict__ out) {
    __shared__ __attribute__((aligned(16))) uint4 ldsAs[2048];        // 32 KB
    __shared__ __attribute__((aligned(16))) unsigned h2pk[2][128];     // 1 KB
    __shared__ __attribute__((aligned(16))) unsigned hp2pk[2][LL][128];// 16 KB
    __shared__ __attribute__((aligned(16))) float pA3[2][2][256];      // 8 KB
    __shared__ __attribute__((aligned(16))) float shint[2][256];       // 2 KB
    __shared__ __attribute__((aligned(16))) unsigned hint8[2][64];     // 512 B
    __shared__ float dqs[2][4];
    __shared__ float fcp[2][2][8];
    __shared__ float sx[2][256];

    const int tid = threadIdx.x;
    const int v = tid >> 6, l = tid & 63;
    const int chA = v >> 2, baseA = (v & 3) << 6;
    const int lr = l & 31, sub = l >> 5;
    const int wB_ = (v << 5) + lr;          // phase-B / gates row
    const int b2 = tid >> 8, w2 = tid & 255; // reduce role
    const int b0 = blockIdx.x * 2;
    const unsigned* __restrict__ wsu = (const unsigned*)ws;

    // ---- persistent weights -> registers (coalesced uint4) ----
    unsigned wAr[112], wB8[96];
    #pragma unroll
    for (int g = 0; g < 28; ++g) {
        uint4 q = ((const uint4*)(wsu + OFF_AR3))[g * 512 + tid];
        wAr[4*g] = q.x; wAr[4*g+1] = q.y; wAr[4*g+2] = q.z; wAr[4*g+3] = q.w;
    }
    #pragma unroll
    for (int g = 0; g < 24; ++g) {
        uint4 q = ((const uint4*)(wsu + OFF_B8))[g * 512 + tid];
        wB8[4*g] = q.x; wB8[4*g+1] = q.y; wB8[4*g+2] = q.z; wB8[4*g+3] = q.w;
    }
    // pin ONCE (opaque def: no remat, no per-step shuttles)
    #pragma unroll
    for (int j = 0; j < 112; ++j) asm volatile("" : "+v"(wAr[j]));
    #pragma unroll
    for (int j = 0; j < 96; ++j) asm volatile("" : "+v"(wB8[j]));

    // ---- LDS init ----
    #pragma unroll
    for (int g = 0; g < 4; ++g)
        ldsAs[g * 512 + tid] = ((const uint4*)(wsu + OFF_AL3))[g * 512 + tid];
    float bA[3], bBi[3], bbh[3], bsr[3];
    #pragma unroll
    for (int g = 0; g < 3; ++g) {
        bA[g]  = ws[OFF_GA + (g << 8) + wB_];
        bBi[g] = ws[OFF_GBI + (g << 8) + wB_];
        bbh[g] = b_hh[(g << 8) + wB_];
        bsr[g] = ws[OFF_SR + (g << 8) + wB_];
    }
    const float wfc0 = W_fc[wB_], wfc1 = W_fc[256 + wB_];
    sx[b2][w2] = x[(b0 + b2) * 256 + w2];
    {
        unsigned* hp = (unsigned*)hp2pk;
        #pragma unroll
        for (int g = 0; g < 8; ++g) hp[g * 512 + tid] = 0u;
        if (tid < 256) ((unsigned*)h2pk)[tid] = 0u;
    }
    const float xc0 = W_xcat[0], xc1 = W_xcat[1];
    const float bf0 = b_fc[0], bf1 = b_fc[1];
    float lp_acc = 0.f;
    __syncthreads();

    for (int i = 0; i < LL; ++i) {
        const int odd = i & 1;
        const int dir = odd ? -1 : 1;
        const int c0g = odd ? (LL - 1) : 0;
        for (int t = 0; t < LL; ++t) {
            const int col = c0g + dir * t;
            const int sidx = (i << 4) + t;

            // ---- Phase A: hint partials, rows r0/r1, k-quarter per lane-half ----
            {
                const uint4* hb0;
                const uint4* hb1;
                if (chA == 0) {
                    hb0 = ((const uint4*)h2pk) + (sub << 4);
                    hb1 = ((const uint4*)h2pk) + 32 + (sub << 4);
                } else {
                    hb0 = ((const uint4*)hp2pk) + (col << 5) + (sub << 4);
                    hb1 = ((const uint4*)hp2pk) + 512 + (col << 5) + (sub << 4);
                }
                float a00=0.f,c00=0.f,a01=0.f,c01=0.f,a10=0.f,c10=0.f,a11=0.f,c11=0.f;
                if (!(chA == 0 && t == 0)) {
                    #pragma unroll
                    for (int g = 0; g < 14; ++g) {
                        uint4 h0 = hb0[g], h1 = hb1[g];
                        a00 = dot2f(wAr[4*g+0], h0.x, a00); c00 = dot2f(wAr[4*g+1], h0.y, c00);
                        a00 = dot2f(wAr[4*g+2], h0.z, a00); c00 = dot2f(wAr[4*g+3], h0.w, c00);
                        a01 = dot2f(wAr[4*g+0], h1.x, a01); c01 = dot2f(wAr[4*g+1], h1.y, c01);
                        a01 = dot2f(wAr[4*g+2], h1.z, a01); c01 = dot2f(wAr[4*g+3], h1.w, c01);
                        a10 = dot2f(wAr[56+4*g+0], h0.x, a10); c10 = dot2f(wAr[56+4*g+1], h0.y, c10);
                        a10 = dot2f(wAr[56+4*g+2], h0.z, a10); c10 = dot2f(wAr[56+4*g+3], h0.w, c10);
                        a11 = dot2f(wAr[56+4*g+0], h1.x, a11); c11 = dot2f(wAr[56+4*g+1], h1.y, c11);
                        a11 = dot2f(wAr[56+4*g+2], h1.z, a11); c11 = dot2f(wAr[56+4*g+3], h1.w, c11);
                    }
                    uint4 wl0 = ldsAs[tid], wl1 = ldsAs[512 + tid];
                    uint4 wl2 = ldsAs[1024 + tid], wl3 = ldsAs[1536 + tid];
                    uint4 h0a = hb0[14], h0b = hb0[15], h1a = hb1[14], h1b = hb1[15];
                    a00 = dot2f(wl0.x, h0a.x, a00); c00 = dot2f(wl0.y, h0a.y, c00);
                    a00 = dot2f(wl0.z, h0a.z, a00); c00 = dot2f(wl0.w, h0a.w, c00);
                    a00 = dot2f(wl1.x, h0b.x, a00); c00 = dot2f(wl1.y, h0b.y, c00);
                    a00 = dot2f(wl1.z, h0b.z, a00); c00 = dot2f(wl1.w, h0b.w, c00);
                    a01 = dot2f(wl0.x, h1a.x, a01); c01 = dot2f(wl0.y, h1a.y, c01);
                    a01 = dot2f(wl0.z, h1a.z, a01); c01 = dot2f(wl0.w, h1a.w, c01);
                    a01 = dot2f(wl1.x, h1b.x, a01); c01 = dot2f(wl1.y, h1b.y, c01);
                    a01 = dot2f(wl1.z, h1b.z, a01); c01 = dot2f(wl1.w, h1b.w, c01);
                    a10 = dot2f(wl2.x, h0a.x, a10); c10 = dot2f(wl2.y, h0a.y, c10);
                    a10 = dot2f(wl2.z, h0a.z, a10); c10 = dot2f(wl2.w, h0a.w, c10);
                    a10 = dot2f(wl3.x, h0b.x, a10); c10 = dot2f(wl3.y, h0b.y, c10);
                    a10 = dot2f(wl3.z, h0b.z, a10); c10 = dot2f(wl3.w, h0b.w, c10);
                    a11 = dot2f(wl2.x, h1a.x, a11); c11 = dot2f(wl2.y, h1a.y, c11);
                    a11 = dot2f(wl2.z, h1a.z, a11); c11 = dot2f(wl2.w, h1a.w, c11);
                    a11 = dot2f(wl3.x, h1b.x, a11); c11 = dot2f(wl3.y, h1b.y, c11);
                    a11 = dot2f(wl3.z, h1b.z, a11); c11 = dot2f(wl3.w, h1b.w, c11);
                }
                a00 += c00; a01 += c01; a10 += c10; a11 += c11;
                a00 += __shfl_xor(a00, 32);
                a01 += __shfl_xor(a01, 32);
                a10 += __shfl_xor(a10, 32);
                a11 += __shfl_xor(a11, 32);
                pA3[chA][sub][baseA + lr]      = sub ? a01 : a00;
                pA3[chA][sub][baseA + 32 + lr] = sub ? a11 : a10;
            }
            __syncthreads();  // B1

            // ---- reduce + quantize hint; prev-step FC finalize ----
            {
                float hi = pA3[0][b2][w2] + pA3[1][b2][w2];
                shint[b2][w2] = hi;
                float am = fabsf(hi);
                #pragma unroll
                for (int o = 1; o < 64; o <<= 1) am = fmaxf(am, __shfl_xor(am, o));
                float qsc = 127.f / fmaxf(am, 1e-20f);
                int q = clampi8(__float2int_rn(hi * qsc));
                ((unsigned char*)hint8)[(b2 << 8) + w2] = (unsigned char)(q & 255);
                if ((w2 & 63) == 0) dqs[b2][w2 >> 6] = am * (1.f / 127.f);

                if (w2 == 0 && sidx > 0) {
                    int ps = sidx - 1, pi2 = ps >> 4, pt2 = ps & 15;
                    int pcol = (pi2 & 1) ? (15 - pt2) : pt2;
                    float l0 = bf0, l1 = bf1;
                    #pragma unroll
                    for (int vv = 0; vv < 8; ++vv) { l0 += fcp[b2][0][vv]; l1 += fcp[b2][1][vv]; }
                    float mx = fmaxf(l0, l1);
                    float lse = mx + logf(__expf(l0 - mx) + __expf(l1 - mx));
                    float xcur = sx[b2][(pi2 << 4) + pcol];
                    float mm = (1.f + xcur) * 0.5f;
                    float lp = (l0 - lse) * mm + (l1 - lse) * (1.f - mm);
                    if (pi2 == 0 && pcol == 0) lp = 1.f - mm;
                    lp_acc += lp;
                }
            }
            __syncthreads();  // B2

            // ---- Phase B + gates + h update + FC (shfl-fused, no pB LDS) ----
            {
                const uint4* hq0 = ((const uint4*)hint8) + (sub << 3);       // chB = sub
                const uint4* hq1 = ((const uint4*)hint8) + 16 + (sub << 3);
                int ra0=0,ra1=0,za0=0,za1=0,na0=0,na1=0;
                int rb0=0,rb1=0,zb0=0,zb1=0,nb0=0,nb1=0;
                #pragma unroll
                for (int gg = 0; gg < 4; ++gg) {
                    uint4 u0 = hq0[gg], u1 = hq1[gg];
                    const int k = gg << 2;
                    ra0 = sdot4(wB8[k],      u0.x, ra0); ra0 = sdot4(wB8[k+1],    u0.y, ra0);
                    ra0 = sdot4(wB8[k+2],    u0.z, ra0); ra0 = sdot4(wB8[k+3],    u0.w, ra0);
                    za0 = sdot4(wB8[32+k],   u0.x, za0); za0 = sdot4(wB8[32+k+1], u0.y, za0);
                    za0 = sdot4(wB8[32+k+2], u0.z, za0); za0 = sdot4(wB8[32+k+3], u0.w, za0);
                    na0 = sdot4(wB8[64+k],   u0.x, na0); na0 = sdot4(wB8[64+k+1], u0.y, na0);
                    na0 = sdot4(wB8[64+k+2], u0.z, na0); na0 = sdot4(wB8[64+k+3], u0.w, na0);
                    ra1 = sdot4(wB8[k],      u1.x, ra1); ra1 = sdot4(wB8[k+1],    u1.y, ra1);
                    ra1 = sdot4(wB8[k+2],    u1.z, ra1); ra1 = sdot4(wB8[k+3],    u1.w, ra1);
                    za1 = sdot4(wB8[32+k],   u1.x, za1); za1 = sdot4(wB8[32+k+1], u1.y, za1);
                    za1 = sdot4(wB8[32+k+2], u1.z, za1); za1 = sdot4(wB8[32+k+3], u1.w, za1);
                    na1 = sdot4(wB8[64+k],   u1.x, na1); na1 = sdot4(wB8[64+k+1], u1.y, na1);
                    na1 = sdot4(wB8[64+k+2], u1.z, na1); na1 = sdot4(wB8[64+k+3], u1.w, na1);
                }
                #pragma unroll
                for (int gg = 4; gg < 8; ++gg) {
                    uint4 u0 = hq0[gg], u1 = hq1[gg];
                    const int k = gg << 2;
                    rb0 = sdot4(wB8[k],      u0.x, rb0); rb0 = sdot4(wB8[k+1],    u0.y, rb0);
                    rb0 = sdot4(wB8[k+2],    u0.z, rb0); rb0 = sdot4(wB8[k+3],    u0.w, rb0);
                    zb0 = sdot4(wB8[32+k],   u0.x, zb0); zb0 = sdot4(wB8[32+k+1], u0.y, zb0);
                    zb0 = sdot4(wB8[32+k+2], u0.z, zb0); zb0 = sdot4(wB8[32+k+3], u0.w, zb0);
                    nb0 = sdot4(wB8[64+k],   u0.x, nb0); nb0 = sdot4(wB8[64+k+1], u0.y, nb0);
                    nb0 = sdot4(wB8[64+k+2], u0.z, nb0); nb0 = sdot4(wB8[64+k+3], u0.w, nb0);
                    rb1 = sdot4(wB8[k],      u1.x, rb1); rb1 = sdot4(wB8[k+1],    u1.y, rb1);
                    rb1 = sdot4(wB8[k+2],    u1.z, rb1); rb1 = sdot4(wB8[k+3],    u1.w, rb1);
                    zb1 = sdot4(wB8[32+k],   u1.x, zb1); zb1 = sdot4(wB8[32+k+1], u1.y, zb1);
                    zb1 = sdot4(wB8[32+k+2], u1.z, zb1); zb1 = sdot4(wB8[32+k+3], u1.w, zb1);
                    nb1 = sdot4(wB8[64+k],   u1.x, nb1); nb1 = sdot4(wB8[64+k+1], u1.y, nb1);
                    nb1 = sdot4(wB8[64+k+2], u1.z, nb1); nb1 = sdot4(wB8[64+k+3], u1.w, nb1);
                }
                const float d00 = dqs[0][2*sub], d01 = dqs[0][2*sub+1];
                const float d10 = dqs[1][2*sub], d11 = dqs[1][2*sub+1];
                float gr0 = (float)ra0 * d00 + (float)rb0 * d01;
                float gz0 = (float)za0 * d00 + (float)zb0 * d01;
                float gn0 = (float)na0 * d00 + (float)nb0 * d01;
                float gr1 = (float)ra1 * d10 + (float)rb1 * d11;
                float gz1 = (float)za1 * d10 + (float)zb1 * d11;
                float gn1 = (float)na1 * d10 + (float)nb1 * d11;
                gr0 += __shfl_xor(gr0, 32); gz0 += __shfl_xor(gz0, 32); gn0 += __shfl_xor(gn0, 32);
                gr1 += __shfl_xor(gr1, 32); gz1 += __shfl_xor(gz1, 32); gn1 += __shfl_xor(gn1, 32);

                const int bsel = sub;
                float GR = (bsel ? gr1 : gr0) * bsr[0];
                float GZ = (bsel ? gz1 : gz0) * bsr[1];
                float GN = (bsel ? gn1 : gn0) * bsr[2];
                float HI = shint[bsel][wB_];
                float xl = (t == 0) ? 0.f : sx[bsel][(i << 4) + col - dir];
                float xu = (i == 0) ? 0.f : sx[bsel][((i - 1) << 4) + col];
                float pu = (xl * xc0 + xu * xc1 + 1.f) * 0.5f;
                float rr_ = fsig(bA[0] * pu + bBi[0] + GR + bbh[0]);
                float zz = fsig(bA[1] * pu + bBi[1] + GZ + bbh[1]);
                float nn = ftanh_(bA[2] * pu + bBi[2] + rr_ * (GN + bbh[2]));
                float hn = (1.f - zz) * nn + zz * HI;
                unsigned short hu = f16b(hn);
                ((unsigned short*)h2pk)[(bsel << 8) + wB_] = hu;
                ((unsigned short*)hp2pk)[(bsel << 12) + (col << 8) + wB_] = hu;
                float s0 = hn * wfc0, s1 = hn * wfc1;
                #pragma unroll
                for (int o = 1; o < 32; o <<= 1) {
                    s0 += __shfl_xor(s0, o);
                    s1 += __shfl_xor(s1, o);
                }
                if (lr == 0) { fcp[bsel][0][v] = s0; fcp[bsel][1][v] = s1; }
            }
            __syncthreads();  // B3
        }
    }

    // ---- final step's FC finalize + output ----
    if (w2 == 0) {
        float l0 = bf0, l1 = bf1;
        #pragma unroll
        for (int vv = 0; vv < 8; ++vv) { l0 += fcp[b2][0][vv]; l1 += fcp[b2][1][vv]; }
        float mx = fmaxf(l0, l1);
        float lse = mx + logf(__expf(l0 - mx) + __expf(l1 - mx));
        float xcur = sx[b2][15 * 16 + 0];   // last step: i=15 (odd) -> col 0
        float mm = (1.f + xcur) * 0.5f;
        lp_acc += (l0 - lse) * mm + (l1 - lse) * (1.f - mm);
        out[b0 + b2] = lp_acc;
    }
}

extern "C" void kernel_launch(void* const* d_in, const int* in_sizes, int n_in,
                              void* d_out, int out_size, void* d_ws, size_t ws_size,
                              hipStream_t stream) {
    const float* x      = (const float*)d_in[0];
    const float* W_ih   = (const float*)d_in[1];
    const float* W_hh   = (const float*)d_in[2];
    const float* b_ih   = (const float*)d_in[3];
    const float* b_hh   = (const float*)d_in[4];
    const float* W_fc   = (const float*)d_in[5];
    const float* b_fc   = (const float*)d_in[6];
    const float* W_hcat = (const float*)d_in[7];
    const float* W_xcat = (const float*)d_in[8];
    float* out = (float*)d_out;
    float* ws  = (float*)d_ws;

    gru2d_prep1<<<768, 64, 0, stream>>>(W_hh, ws);
    gru2d_prep2<<<452, 256, 0, stream>>>(W_ih, W_hh, b_ih, W_hcat, ws);
    gru2d_main<<<256, 512, 0, stream>>>(x, b_hh, W_fc, b_fc, W_xcat, ws, out);
}

// Round 7
// 3863.643 us; speedup vs baseline: 1.1302x; 1.1302x over previous
//
#include <hip/hip_runtime.h>
#include <math.h>

#define LL 16
#define WD 256
#define G3 768

// ws layout (u32 units)
#define OFF_AR3 0        // 36864 u32 : A f16 pairs, reg part (18 uint4/thread: 36/row x 2 rows)
#define OFF_AL3 36864    // 28672 u32 : A f16 pairs, LDS part (14 uint4/thread: 28/row x 2 rows)
#define OFF_B8  65536    // 49152 u32 : W_hh int8 (24 uint4/thread)
#define OFF_SR  114688   // 768 f32 : per-row scale of W_hh
#define OFF_GA  115456   // 768 f32 : W_ih[:,0]-W_ih[:,1]
#define OFF_GBI 116224   // 768 f32 : W_ih[:,1]+b_ih

typedef _Float16 h2v __attribute__((ext_vector_type(2)));

__device__ __forceinline__ unsigned packh2(float a, float b) {
    h2v v; v.x = (_Float16)a; v.y = (_Float16)b;
    return __builtin_bit_cast(unsigned, v);
}
__device__ __forceinline__ float dot2f(unsigned w, unsigned h, float acc) {
#if __has_builtin(__builtin_amdgcn_fdot2)
    return __builtin_amdgcn_fdot2(__builtin_bit_cast(h2v, w),
                                  __builtin_bit_cast(h2v, h), acc, false);
#else
    h2v a = __builtin_bit_cast(h2v, w), b = __builtin_bit_cast(h2v, h);
    return acc + (float)a.x * (float)b.x + (float)a.y * (float)b.y;
#endif
}
__device__ __forceinline__ int sdot4(unsigned a, unsigned b, int acc) {
#if __has_builtin(__builtin_amdgcn_sdot4)
    return __builtin_amdgcn_sdot4((int)a, (int)b, acc, false);
#else
    int s = acc;
    #pragma unroll
    for (int r = 0; r < 4; ++r)
        s += (int)(signed char)(a >> (8 * r)) * (int)(signed char)(b >> (8 * r));
    return s;
#endif
}
__device__ __forceinline__ unsigned short f16b(float v) {
    _Float16 h = (_Float16)v; return __builtin_bit_cast(unsigned short, h);
}
__device__ __forceinline__ float fsig(float v) { return 1.f / (1.f + __expf(-v)); }
__device__ __forceinline__ float ftanh_(float v) {
    v = fminf(fmaxf(v, -15.f), 15.f);
    float e = __expf(-2.f * v);
    return (1.f - e) / (1.f + e);
}
__device__ __forceinline__ int clampi8(int q) {
    return q > 127 ? 127 : (q < -127 ? -127 : q);
}

// per-row max-abs of W_hh -> scale
__global__ __launch_bounds__(64)
void gru2d_prep1(const float* __restrict__ W_hh, float* __restrict__ ws) {
    int row = blockIdx.x, lane = threadIdx.x;
    float s = 0.f;
    for (int k = lane; k < 256; k += 64) s = fmaxf(s, fabsf(W_hh[row * 256 + k]));
    #pragma unroll
    for (int o = 32; o > 0; o >>= 1) s = fmaxf(s, __shfl_down(s, o));
    if (lane == 0) ws[OFF_SR + row] = (s > 0.f) ? s * (1.f / 127.f) : 1.f;
}

// Main-kernel thread t: v=t>>6 (wave), l=t&63.
// Phase A role: chA=v>>2, baseA=(v&3)*64, rows r0=baseA+(l&31), r1=r0+32,
//   k-quarter koff = chA*256 + (l>>5)*128 f16 (concat-k of [Wh_l|Wh_u]).
//   Per row 64 pair-u32 jj in [0,64): jj<36 in regs (wAr[rs*36+jj]), jj>=36 in LDS
//   (ldsA2[(rs*7 + (jj-36)/4)*512 + t], lane component (jj-36)&3).
// Phase B role: wB=v*32+(l&31), chB=l>>5; gate rows {wB,256+wB,512+wB},
//   k in [chB*128,+128) as i8: wB8[gate*32+q].
__global__ __launch_bounds__(256)
void gru2d_prep2(const float* __restrict__ W_ih, const float* __restrict__ W_hh,
                 const float* __restrict__ b_ih, const float* __restrict__ W_hcat,
                 float* __restrict__ ws) {
    unsigned* __restrict__ wsu = (unsigned*)ws;
    int m = blockIdx.x * 256 + threadIdx.x;
    if (m < 36864) {
        int g = m >> 11, t = (m >> 2) & 511, rr = m & 3;
        int jl = g * 4 + rr;                 // [0,72)
        int rs = (jl >= 36) ? 1 : 0;
        int jj = jl - 36 * rs;               // [0,36)
        int v = t >> 6, l = t & 63;
        int chA = v >> 2, baseA = (v & 3) * 64;
        int r = baseA + (l & 31) + 32 * rs;
        int koff = chA * 256 + (l >> 5) * 128;
        int pb = r * 512 + koff + 2 * jj;
        wsu[OFF_AR3 + m] = packh2(W_hcat[pb], W_hcat[pb + 1]);
    } else if (m < 65536) {
        int mm = m - 36864;
        int g = mm >> 11, t = (mm >> 2) & 511, rr = mm & 3;
        int jl2 = g * 4 + rr;                // [0,56)
        int rs = (jl2 >= 28) ? 1 : 0;
        int jj = 36 + jl2 - 28 * rs;         // [36,64)
        int v = t >> 6, l = t & 63;
        int chA = v >> 2, baseA = (v & 3) * 64;
        int r = baseA + (l & 31) + 32 * rs;
        int koff = chA * 256 + (l >> 5) * 128;
        int pb = r * 512 + koff + 2 * jj;
        wsu[OFF_AL3 + mm] = packh2(W_hcat[pb], W_hcat[pb + 1]);
    } else if (m < 114688) {
        int mm = m - 65536;
        int g4 = mm >> 11, t = (mm >> 2) & 511, rr = mm & 3;
        int ql = g4 * 4 + rr;
        int gate = ql >> 5, q = ql & 31;
        int v = t >> 6, l = t & 63;
        int wB_ = v * 32 + (l & 31), chB = l >> 5;
        int row = gate * 256 + wB_;
        float inv = 1.f / ws[OFF_SR + row];
        int kb = row * 256 + chB * 128 + 4 * q;
        unsigned pk = 0;
        #pragma unroll
        for (int bb = 0; bb < 4; ++bb) {
            int qv = clampi8(__float2int_rn(W_hh[kb + bb] * inv));
            pk |= ((unsigned)(qv & 255)) << (8 * bb);
        }
        wsu[OFF_B8 + mm] = pk;
    } else if (m < 115456) {
        int e = m - 114688;
        float w0 = W_ih[2 * e], w1 = W_ih[2 * e + 1];
        ws[OFF_GA + e] = w0 - w1;
        ws[OFF_GBI + e] = w1 + b_ih[e];
    }
}

// 512 threads (2 waves/SIMD, 256-reg pool), 1 block/CU, 2 batches/block.
// 3 barriers/step; cross-k reductions via shfl_xor(32); 168 reg-resident weights
// (R5-proven budget) + 112KB LDS A-slice.
__global__ __launch_bounds__(512, 2)
void gru2d_main(const float* __restrict__ x, const float* __restrict__ b_hh,
                const float* __restrict__ W_fc, const float* __restrict__ b_fc,
                const float* __restrict__ W_xcat, const float* __restrict__ ws,
                float* __restrict__ out) {
    __shared__ __attribute__((aligned(16))) uint4 ldsA2[14 * 512];     // 112 KB
    __shared__ __attribute__((aligned(16))) unsigned h2pk[2][128];      // 1 KB
    __shared__ __attribute__((aligned(16))) unsigned hp2pk[2][LL][128]; // 16 KB
    __shared__ __attribute__((aligned(16))) float pA3[2][2][256];       // 8 KB
    __shared__ __attribute__((aligned(16))) float shint[2][256];        // 2 KB
    __shared__ __attribute__((aligned(16))) unsigned hint8[2][64];      // 512 B
    __shared__ float dqs[2][4];
    __shared__ float fcp[2][2][8];
    __shared__ float sx[2][256];

    const int tid = threadIdx.x;
    const int v = tid >> 6, l = tid & 63;
    const int chA = v >> 2, baseA = (v & 3) << 6;
    const int lr = l & 31, sub = l >> 5;
    const int wB_ = (v << 5) + lr;           // phase-B / gates row
    const int b2 = tid >> 8, w2 = tid & 255; // reduce role
    const int b0 = blockIdx.x * 2;
    const unsigned* __restrict__ wsu = (const unsigned*)ws;

    // ---- persistent weights -> registers (coalesced uint4) ----
    unsigned wAr[72], wB8[96];
    #pragma unroll
    for (int g = 0; g < 18; ++g) {
        uint4 q = ((const uint4*)(wsu + OFF_AR3))[g * 512 + tid];
        wAr[4*g] = q.x; wAr[4*g+1] = q.y; wAr[4*g+2] = q.z; wAr[4*g+3] = q.w;
    }
    #pragma unroll
    for (int g = 0; g < 24; ++g) {
        uint4 q = ((const uint4*)(wsu + OFF_B8))[g * 512 + tid];
        wB8[4*g] = q.x; wB8[4*g+1] = q.y; wB8[4*g+2] = q.z; wB8[4*g+3] = q.w;
    }
    // pin ONCE (opaque def: breaks remat; 168 regs fits the 256 budget - R5-proven)
    #pragma unroll
    for (int j = 0; j < 72; ++j) asm volatile("" : "+v"(wAr[j]));
    #pragma unroll
    for (int j = 0; j < 96; ++j) asm volatile("" : "+v"(wB8[j]));

    // ---- LDS init ----
    #pragma unroll
    for (int g = 0; g < 14; ++g)
        ldsA2[g * 512 + tid] = ((const uint4*)(wsu + OFF_AL3))[g * 512 + tid];
    float bA[3], bBi[3], bbh[3], bsr[3];
    #pragma unroll
    for (int g = 0; g < 3; ++g) {
        bA[g]  = ws[OFF_GA + (g << 8) + wB_];
        bBi[g] = ws[OFF_GBI + (g << 8) + wB_];
        bbh[g] = b_hh[(g << 8) + wB_];
        bsr[g] = ws[OFF_SR + (g << 8) + wB_];
    }
    const float wfc0 = W_fc[wB_], wfc1 = W_fc[256 + wB_];
    sx[b2][w2] = x[(b0 + b2) * 256 + w2];
    {
        unsigned* hp = (unsigned*)hp2pk;
        #pragma unroll
        for (int g = 0; g < 8; ++g) hp[g * 512 + tid] = 0u;
        if (tid < 256) ((unsigned*)h2pk)[tid] = 0u;
    }
    const float xc0 = W_xcat[0], xc1 = W_xcat[1];
    const float bf0 = b_fc[0], bf1 = b_fc[1];
    float lp_acc = 0.f;
    __syncthreads();

    for (int i = 0; i < LL; ++i) {
        const int odd = i & 1;
        const int dir = odd ? -1 : 1;
        const int c0g = odd ? (LL - 1) : 0;
        for (int t = 0; t < LL; ++t) {
            const int col = c0g + dir * t;
            const int sidx = (i << 4) + t;

            // ---- Phase A: hint partials, rows r0/r1, k-quarter per lane-half ----
            {
                const uint4* hb0;
                const uint4* hb1;
                if (chA == 0) {
                    hb0 = ((const uint4*)h2pk) + (sub << 4);
                    hb1 = ((const uint4*)h2pk) + 32 + (sub << 4);
                } else {
                    hb0 = ((const uint4*)hp2pk) + (col << 5) + (sub << 4);
                    hb1 = ((const uint4*)hp2pk) + 512 + (col << 5) + (sub << 4);
                }
                float a00=0.f,c00=0.f,a01=0.f,c01=0.f,a10=0.f,c10=0.f,a11=0.f,c11=0.f;
                if (!(chA == 0 && t == 0)) {
                    #pragma unroll
                    for (int g = 0; g < 9; ++g) {        // reg part: jj 0..35 per row
                        uint4 h0 = hb0[g], h1 = hb1[g];
                        a00 = dot2f(wAr[4*g+0], h0.x, a00); c00 = dot2f(wAr[4*g+1], h0.y, c00);
                        a00 = dot2f(wAr[4*g+2], h0.z, a00); c00 = dot2f(wAr[4*g+3], h0.w, c00);
                        a01 = dot2f(wAr[4*g+0], h1.x, a01); c01 = dot2f(wAr[4*g+1], h1.y, c01);
                        a01 = dot2f(wAr[4*g+2], h1.z, a01); c01 = dot2f(wAr[4*g+3], h1.w, c01);
                        a10 = dot2f(wAr[36+4*g+0], h0.x, a10); c10 = dot2f(wAr[36+4*g+1], h0.y, c10);
                        a10 = dot2f(wAr[36+4*g+2], h0.z, a10); c10 = dot2f(wAr[36+4*g+3], h0.w, c10);
                        a11 = dot2f(wAr[36+4*g+0], h1.x, a11); c11 = dot2f(wAr[36+4*g+1], h1.y, c11);
                        a11 = dot2f(wAr[36+4*g+2], h1.z, a11); c11 = dot2f(wAr[36+4*g+3], h1.w, c11);
                    }
                    #pragma unroll
                    for (int g = 0; g < 7; ++g) {        // LDS part: jj 36..63 per row
                        uint4 wl0 = ldsA2[g * 512 + tid];
                        uint4 wl1 = ldsA2[(7 + g) * 512 + tid];
                        uint4 h0 = hb0[9 + g], h1 = hb1[9 + g];
                        a00 = dot2f(wl0.x, h0.x, a00); c00 = dot2f(wl0.y, h0.y, c00);
                        a00 = dot2f(wl0.z, h0.z, a00); c00 = dot2f(wl0.w, h0.w, c00);
                        a01 = dot2f(wl0.x, h1.x, a01); c01 = dot2f(wl0.y, h1.y, c01);
                        a01 = dot2f(wl0.z, h1.z, a01); c01 = dot2f(wl0.w, h1.w, c01);
                        a10 = dot2f(wl1.x, h0.x, a10); c10 = dot2f(wl1.y, h0.y, c10);
                        a10 = dot2f(wl1.z, h0.z, a10); c10 = dot2f(wl1.w, h0.w, c10);
                        a11 = dot2f(wl1.x, h1.x, a11); c11 = dot2f(wl1.y, h1.y, c11);
                        a11 = dot2f(wl1.z, h1.z, a11); c11 = dot2f(wl1.w, h1.w, c11);
                    }
                }
                a00 += c00; a01 += c01; a10 += c10; a11 += c11;
                a00 += __shfl_xor(a00, 32);
                a01 += __shfl_xor(a01, 32);
                a10 += __shfl_xor(a10, 32);
                a11 += __shfl_xor(a11, 32);
                pA3[chA][sub][baseA + lr]      = sub ? a01 : a00;
                pA3[chA][sub][baseA + 32 + lr] = sub ? a11 : a10;
            }
            __syncthreads();  // B1

            // ---- reduce + quantize hint; prev-step FC finalize ----
            {
                float hi = pA3[0][b2][w2] + pA3[1][b2][w2];
                shint[b2][w2] = hi;
                float am = fabsf(hi);
                #pragma unroll
                for (int o = 1; o < 64; o <<= 1) am = fmaxf(am, __shfl_xor(am, o));
                float qsc = 127.f / fmaxf(am, 1e-20f);
                int q = clampi8(__float2int_rn(hi * qsc));
                ((unsigned char*)hint8)[(b2 << 8) + w2] = (unsigned char)(q & 255);
                if ((w2 & 63) == 0) dqs[b2][w2 >> 6] = am * (1.f / 127.f);

                if (w2 == 0 && sidx > 0) {
                    int ps = sidx - 1, pi2 = ps >> 4, pt2 = ps & 15;
                    int pcol = (pi2 & 1) ? (15 - pt2) : pt2;
                    float l0 = bf0, l1 = bf1;
                    #pragma unroll
                    for (int vv = 0; vv < 8; ++vv) { l0 += fcp[b2][0][vv]; l1 += fcp[b2][1][vv]; }
                    float mx = fmaxf(l0, l1);
                    float lse = mx + logf(__expf(l0 - mx) + __expf(l1 - mx));
                    float xcur = sx[b2][(pi2 << 4) + pcol];
                    float mm = (1.f + xcur) * 0.5f;
                    float lp = (l0 - lse) * mm + (l1 - lse) * (1.f - mm);
                    if (pi2 == 0 && pcol == 0) lp = 1.f - mm;
                    lp_acc += lp;
                }
            }
            __syncthreads();  // B2

            // ---- Phase B + gates + h update + FC (shfl-fused, no pB LDS) ----
            {
                const uint4* hq0 = ((const uint4*)hint8) + (sub << 3);       // chB = sub
                const uint4* hq1 = ((const uint4*)hint8) + 16 + (sub << 3);
                int ra0=0,ra1=0,za0=0,za1=0,na0=0,na1=0;
                int rb0=0,rb1=0,zb0=0,zb1=0,nb0=0,nb1=0;
                #pragma unroll
                for (int gg = 0; gg < 4; ++gg) {
                    uint4 u0 = hq0[gg], u1 = hq1[gg];
                    const int k = gg << 2;
                    ra0 = sdot4(wB8[k],      u0.x, ra0); ra0 = sdot4(wB8[k+1],    u0.y, ra0);
                    ra0 = sdot4(wB8[k+2],    u0.z, ra0); ra0 = sdot4(wB8[k+3],    u0.w, ra0);
                    za0 = sdot4(wB8[32+k],   u0.x, za0); za0 = sdot4(wB8[32+k+1], u0.y, za0);
                    za0 = sdot4(wB8[32+k+2], u0.z, za0); za0 = sdot4(wB8[32+k+3], u0.w, za0);
                    na0 = sdot4(wB8[64+k],   u0.x, na0); na0 = sdot4(wB8[64+k+1], u0.y, na0);
                    na0 = sdot4(wB8[64+k+2], u0.z, na0); na0 = sdot4(wB8[64+k+3], u0.w, na0);
                    ra1 = sdot4(wB8[k],      u1.x, ra1); ra1 = sdot4(wB8[k+1],    u1.y, ra1);
                    ra1 = sdot4(wB8[k+2],    u1.z, ra1); ra1 = sdot4(wB8[k+3],    u1.w, ra1);
                    za1 = sdot4(wB8[32+k],   u1.x, za1); za1 = sdot4(wB8[32+k+1], u1.y, za1);
                    za1 = sdot4(wB8[32+k+2], u1.z, za1); za1 = sdot4(wB8[32+k+3], u1.w, za1);
                    na1 = sdot4(wB8[64+k],   u1.x, na1); na1 = sdot4(wB8[64+k+1], u1.y, na1);
                    na1 = sdot4(wB8[64+k+2], u1.z, na1); na1 = sdot4(wB8[64+k+3], u1.w, na1);
                }
                #pragma unroll
                for (int gg = 4; gg < 8; ++gg) {
                    uint4 u0 = hq0[gg], u1 = hq1[gg];
                    const int k = gg << 2;
                    rb0 = sdot4(wB8[k],      u0.x, rb0); rb0 = sdot4(wB8[k+1],    u0.y, rb0);
                    rb0 = sdot4(wB8[k+2],    u0.z, rb0); rb0 = sdot4(wB8[k+3],    u0.w, rb0);
                    zb0 = sdot4(wB8[32+k],   u0.x, zb0); zb0 = sdot4(wB8[32+k+1], u0.y, zb0);
                    zb0 = sdot4(wB8[32+k+2], u0.z, zb0); zb0 = sdot4(wB8[32+k+3], u0.w, zb0);
                    nb0 = sdot4(wB8[64+k],   u0.x, nb0); nb0 = sdot4(wB8[64+k+1], u0.y, nb0);
                    nb0 = sdot4(wB8[64+k+2], u0.z, nb0); nb0 = sdot4(wB8[64+k+3], u0.w, nb0);
                    rb1 = sdot4(wB8[k],      u1.x, rb1); rb1 = sdot4(wB8[k+1],    u1.y, rb1);
                    rb1 = sdot4(wB8[k+2],    u1.z, rb1); rb1 = sdot4(wB8[k+3],    u1.w, rb1);
                    zb1 = sdot4(wB8[32+k],   u1.x, zb1); zb1 = sdot4(wB8[32+k+1], u1.y, zb1);
                    zb1 = sdot4(wB8[32+k+2], u1.z, zb1); zb1 = sdot4(wB8[32+k+3], u1.w, zb1);
                    nb1 = sdot4(wB8[64+k],   u1.x, nb1); nb1 = sdot4(wB8[64+k+1], u1.y, nb1);
                    nb1 = sdot4(wB8[64+k+2], u1.z, nb1); nb1 = sdot4(wB8[64+k+3], u1.w, nb1);
                }
                const float d00 = dqs[0][2*sub], d01 = dqs[0][2*sub+1];
                const float d10 = dqs[1][2*sub], d11 = dqs[1][2*sub+1];
                float gr0 = (float)ra0 * d00 + (float)rb0 * d01;
                float gz0 = (float)za0 * d00 + (float)zb0 * d01;
                float gn0 = (float)na0 * d00 + (float)nb0 * d01;
                float gr1 = (float)ra1 * d10 + (float)rb1 * d11;
                float gz1 = (float)za1 * d10 + (float)zb1 * d11;
                float gn1 = (float)na1 * d10 + (float)nb1 * d11;
                gr0 += __shfl_xor(gr0, 32); gz0 += __shfl_xor(gz0, 32); gn0 += __shfl_xor(gn0, 32);
                gr1 += __shfl_xor(gr1, 32); gz1 += __shfl_xor(gz1, 32); gn1 += __shfl_xor(gn1, 32);

                const int bsel = sub;
                float GR = (bsel ? gr1 : gr0) * bsr[0];
                float GZ = (bsel ? gz1 : gz0) * bsr[1];
                float GN = (bsel ? gn1 : gn0) * bsr[2];
                float HI = shint[bsel][wB_];
                float xl = (t == 0) ? 0.f : sx[bsel][(i << 4) + col - dir];
                float xu = (i == 0) ? 0.f : sx[bsel][((i - 1) << 4) + col];
                float pu = (xl * xc0 + xu * xc1 + 1.f) * 0.5f;
                float rr_ = fsig(bA[0] * pu + bBi[0] + GR + bbh[0]);
                float zz = fsig(bA[1] * pu + bBi[1] + GZ + bbh[1]);
                float nn = ftanh_(bA[2] * pu + bBi[2] + rr_ * (GN + bbh[2]));
                float hn = (1.f - zz) * nn + zz * HI;
                unsigned short hu = f16b(hn);
                ((unsigned short*)h2pk)[(bsel << 8) + wB_] = hu;
                ((unsigned short*)hp2pk)[(bsel << 12) + (col << 8) + wB_] = hu;
                float s0 = hn * wfc0, s1 = hn * wfc1;
                #pragma unroll
                for (int o = 1; o < 32; o <<= 1) {
                    s0 += __shfl_xor(s0, o);
                    s1 += __shfl_xor(s1, o);
                }
                if (lr == 0) { fcp[bsel][0][v] = s0; fcp[bsel][1][v] = s1; }
            }
            __syncthreads();  // B3
        }
    }

    // ---- final step's FC finalize + output ----
    if (w2 == 0) {
        float l0 = bf0, l1 = bf1;
        #pragma unroll
        for (int vv = 0; vv < 8; ++vv) { l0 += fcp[b2][0][vv]; l1 += fcp[b2][1][vv]; }
        float mx = fmaxf(l0, l1);
        float lse = mx + logf(__expf(l0 - mx) + __expf(l1 - mx));
        float xcur = sx[b2][15 * 16 + 0];   // last step: i=15 (odd) -> col 0
        float mm = (1.f + xcur) * 0.5f;
        lp_acc += (l0 - lse) * mm + (l1 - lse) * (1.f - mm);
        out[b0 + b2] = lp_acc;
    }
}

extern "C" void kernel_launch(void* const* d_in, const int* in_sizes, int n_in,
                              void* d_out, int out_size, void* d_ws, size_t ws_size,
                              hipStream_t stream) {
    const float* x      = (const float*)d_in[0];
    const float* W_ih   = (const float*)d_in[1];
    const float* W_hh   = (const float*)d_in[2];
    const float* b_ih   = (const float*)d_in[3];
    const float* b_hh   = (const float*)d_in[4];
    const float* W_fc   = (const float*)d_in[5];
    const float* b_fc   = (const float*)d_in[6];
    const float* W_hcat = (const float*)d_in[7];
    const float* W_xcat = (const float*)d_in[8];
    float* out = (float*)d_out;
    float* ws  = (float*)d_ws;

    gru2d_prep1<<<768, 64, 0, stream>>>(W_hh, ws);
    gru2d_prep2<<<452, 256, 0, stream>>>(W_ih, W_hh, b_ih, W_hcat, ws);
    gru2d_main<<<256, 512, 0, stream>>>(x, b_hh, W_fc, b_fc, W_xcat, ws, out);
}

// Round 8
// 973.259 us; speedup vs baseline: 4.4866x; 3.9698x over previous
//
#include <hip/hip_runtime.h>
#include <math.h>

#define LL 16
#define WD 256
#define G3 768

// ws layout (u32 units)
#define OFF_AR  0        // 36864 u32 : A f16 pairs, reg part (18 uint4/thread)
#define OFF_AL  36864    // 28672 u32 : A f16 pairs, LDS part (14 uint4/thread)
#define OFF_B8  65536    // 49152 u32 : W_hh int8 (24 uint4/thread)
#define OFF_SR  114688   // 768 f32 : per-row scale of W_hh
#define OFF_GA  115456   // 768 f32 : W_ih[:,0]-W_ih[:,1]
#define OFF_GBI 116224   // 768 f32 : W_ih[:,1]+b_ih

typedef _Float16 h2v __attribute__((ext_vector_type(2)));

__device__ __forceinline__ unsigned packh2(float a, float b) {
    h2v v; v.x = (_Float16)a; v.y = (_Float16)b;
    return __builtin_bit_cast(unsigned, v);
}
__device__ __forceinline__ float dot2f(unsigned w, unsigned h, float acc) {
#if __has_builtin(__builtin_amdgcn_fdot2)
    return __builtin_amdgcn_fdot2(__builtin_bit_cast(h2v, w),
                                  __builtin_bit_cast(h2v, h), acc, false);
#else
    h2v a = __builtin_bit_cast(h2v, w), b = __builtin_bit_cast(h2v, h);
    return acc + (float)a.x * (float)b.x + (float)a.y * (float)b.y;
#endif
}
__device__ __forceinline__ int sdot4(unsigned a, unsigned b, int acc) {
#if __has_builtin(__builtin_amdgcn_sdot4)
    return __builtin_amdgcn_sdot4((int)a, (int)b, acc, false);
#else
    int s = acc;
    #pragma unroll
    for (int r = 0; r < 4; ++r)
        s += (int)(signed char)(a >> (8 * r)) * (int)(signed char)(b >> (8 * r));
    return s;
#endif
}
__device__ __forceinline__ unsigned short f16b(float v) {
    _Float16 h = (_Float16)v; return __builtin_bit_cast(unsigned short, h);
}
__device__ __forceinline__ float fsig(float v) { return 1.f / (1.f + __expf(-v)); }
__device__ __forceinline__ float ftanh_(float v) {
    v = fminf(fmaxf(v, -15.f), 15.f);
    float e = __expf(-2.f * v);
    return (1.f - e) / (1.f + e);
}
__device__ __forceinline__ int clampi8(int q) {
    return q > 127 ? 127 : (q < -127 ? -127 : q);
}

// per-row max-abs of W_hh -> scale
__global__ __launch_bounds__(64)
void gru2d_prep1(const float* __restrict__ W_hh, float* __restrict__ ws) {
    int row = blockIdx.x, lane = threadIdx.x;
    float s = 0.f;
    for (int k = lane; k < 256; k += 64) s = fmaxf(s, fabsf(W_hh[row * 256 + k]));
    #pragma unroll
    for (int o = 32; o > 0; o >>= 1) s = fmaxf(s, __shfl_down(s, o));
    if (lane == 0) ws[OFF_SR + row] = (s > 0.f) ? s * (1.f / 127.f) : 1.f;
}

// A layout (R5-proven, Phase-A role thread t: w=t&255, ch=t>>8):
//   row w of [Wh_l|Wh_u], concat-k half [ch*256,+256) as 128 f16-pairs j:
//   j<72 in regs (AR, [(g)*512+t]*4+r, j=g*4+r), j>=72 in LDS (AL).
// B layout (Phase-B role thread t: v=t>>6, l=t&63, wB=v*32+(l&31), chB=l>>5):
//   gate rows {wB,256+wB,512+wB} of W_hh as i8, k in [chB*128,+128):
//   wB8[gate*32+q], stored [(g4)*512+t]*4+r, q=g4*4+r.
__global__ __launch_bounds__(256)
void gru2d_prep2(const float* __restrict__ W_ih, const float* __restrict__ W_hh,
                 const float* __restrict__ b_ih, const float* __restrict__ W_hcat,
                 float* __restrict__ ws) {
    unsigned* __restrict__ wsu = (unsigned*)ws;
    int m = blockIdx.x * 256 + threadIdx.x;
    if (m < 36864) {
        int g = m >> 11, t5 = (m >> 2) & 511, r = m & 3;
        int w = t5 & 255, ch = t5 >> 8, j = g * 4 + r;
        int base = w * 512 + ch * 256 + 2 * j;
        wsu[OFF_AR + m] = packh2(W_hcat[base], W_hcat[base + 1]);
    } else if (m < 65536) {
        int mm = m - 36864;
        int g = mm >> 11, t5 = (mm >> 2) & 511, r = mm & 3;
        int w = t5 & 255, ch = t5 >> 8, j = 72 + g * 4 + r;
        int base = w * 512 + ch * 256 + 2 * j;
        wsu[OFF_AL + mm] = packh2(W_hcat[base], W_hcat[base + 1]);
    } else if (m < 114688) {
        int mm = m - 65536;
        int g4 = mm >> 11, t = (mm >> 2) & 511, rr = mm & 3;
        int ql = g4 * 4 + rr;
        int gate = ql >> 5, q = ql & 31;
        int v = t >> 6, l = t & 63;
        int wB_ = v * 32 + (l & 31), chB = l >> 5;
        int row = gate * 256 + wB_;
        float inv = 1.f / ws[OFF_SR + row];
        int kb = row * 256 + chB * 128 + 4 * q;
        unsigned pk = 0;
        #pragma unroll
        for (int bb = 0; bb < 4; ++bb) {
            int qv = clampi8(__float2int_rn(W_hh[kb + bb] * inv));
            pk |= ((unsigned)(qv & 255)) << (8 * bb);
        }
        wsu[OFF_B8 + mm] = pk;
    } else if (m < 115456) {
        int e = m - 114688;
        float w0 = W_ih[2 * e], w1 = W_ih[2 * e + 1];
        ws[OFF_GA + e] = w0 - w1;
        ws[OFF_GBI + e] = w1 + b_ih[e];
    }
}

// 512 threads (2 waves/SIMD), 1 block/CU, 2 batches/block.
// Phase A = R5-proven (per-step pins -> no spill). Phase B fused with gates,
// h-update, FC via shfl_xor(32); 3 barriers/step; deferred FC finalize.
__global__ __launch_bounds__(512, 2)
void gru2d_main(const float* __restrict__ x, const float* __restrict__ b_hh,
                const float* __restrict__ W_fc, const float* __restrict__ b_fc,
                const float* __restrict__ W_xcat, const float* __restrict__ ws,
                float* __restrict__ out) {
    __shared__ __attribute__((aligned(16))) uint4 ldsA[14 * 512];       // 112 KB
    __shared__ __attribute__((aligned(16))) unsigned h2pk[2][128];       // 1 KB
    __shared__ __attribute__((aligned(16))) unsigned hp2pk[2][LL][128];  // 16 KB
    __shared__ __attribute__((aligned(16))) float pA[2][2][256];         // 8 KB
    __shared__ __attribute__((aligned(16))) float shint[2][256];         // 2 KB
    __shared__ __attribute__((aligned(16))) unsigned hint8[2][64];       // 512 B
    __shared__ float dqs[2][4];
    __shared__ float fcp[2][2][8];
    __shared__ float sx[2][256];

    const int tid = threadIdx.x;
    const int w = tid & 255;
    const int ch = tid >> 8;                 // Phase A / reduce role (wave-uniform)
    const int v = tid >> 6, l = tid & 63;
    const int lr = l & 31, sub = l >> 5;
    const int wB_ = (v << 5) + lr;           // Phase B / gates / FC role
    const int b0 = blockIdx.x * 2;
    const unsigned* __restrict__ wsu = (const unsigned*)ws;

    // ---- persistent weights -> registers (coalesced uint4) ----
    unsigned wA[72], wB8[96];
    #pragma unroll
    for (int g = 0; g < 18; ++g) {
        uint4 q = ((const uint4*)(wsu + OFF_AR))[g * 512 + tid];
        wA[4*g] = q.x; wA[4*g+1] = q.y; wA[4*g+2] = q.z; wA[4*g+3] = q.w;
    }
    #pragma unroll
    for (int g = 0; g < 24; ++g) {
        uint4 q = ((const uint4*)(wsu + OFF_B8))[g * 512 + tid];
        wB8[4*g] = q.x; wB8[4*g+1] = q.y; wB8[4*g+2] = q.z; wB8[4*g+3] = q.w;
    }

    // ---- LDS init ----
    #pragma unroll
    for (int g = 0; g < 14; ++g)
        ldsA[g * 512 + tid] = ((const uint4*)(wsu + OFF_AL))[g * 512 + tid];
    float bA[3], bBi[3], bbh[3], bsr[3];
    #pragma unroll
    for (int g = 0; g < 3; ++g) {
        bA[g]  = ws[OFF_GA + (g << 8) + wB_];
        bBi[g] = ws[OFF_GBI + (g << 8) + wB_];
        bbh[g] = b_hh[(g << 8) + wB_];
        bsr[g] = ws[OFF_SR + (g << 8) + wB_];
    }
    const float wfc0 = W_fc[wB_], wfc1 = W_fc[256 + wB_];
    sx[ch][w] = x[(b0 + ch) * 256 + w];
    {
        unsigned* hp = (unsigned*)hp2pk;
        #pragma unroll
        for (int g = 0; g < 8; ++g) hp[g * 512 + tid] = 0u;
        if (tid < 256) ((unsigned*)h2pk)[tid] = 0u;
    }
    const float xc0 = W_xcat[0], xc1 = W_xcat[1];
    const float bf0 = b_fc[0], bf1 = b_fc[1];
    float lp_acc = 0.f;
    __syncthreads();

    for (int i = 0; i < LL; ++i) {
        const int odd = i & 1;
        const int dir = odd ? -1 : 1;
        const int c0g = odd ? (LL - 1) : 0;
        for (int t = 0; t < LL; ++t) {
            const int col = c0g + dir * t;
            const int sidx = (i << 4) + t;

            // per-step pins: USE+DEF each iteration makes spilling cost a
            // store+load per step -> allocator keeps weights resident (R5-proven)
            #pragma unroll
            for (int g = 0; g < 18; ++g)
                asm volatile("" : "+v"(wA[4*g]), "+v"(wA[4*g+1]), "+v"(wA[4*g+2]), "+v"(wA[4*g+3]));
            #pragma unroll
            for (int g = 0; g < 24; ++g)
                asm volatile("" : "+v"(wB8[4*g]), "+v"(wB8[4*g+1]), "+v"(wB8[4*g+2]), "+v"(wB8[4*g+3]));

            // ---- Phase A (R5 structure): hint partials, row w, k-half ch ----
            {
                const uint4* hb0;
                const uint4* hb1;
                if (ch == 0) {
                    hb0 = (const uint4*)h2pk;
                    hb1 = ((const uint4*)h2pk) + 32;
                } else {
                    hb0 = ((const uint4*)hp2pk) + (col << 5);
                    hb1 = ((const uint4*)hp2pk) + 512 + (col << 5);
                }
                float a0 = 0.f, c0 = 0.f, a1 = 0.f, c1 = 0.f;
                if (!(ch == 0 && t == 0)) {
                    #pragma unroll
                    for (int g = 0; g < 18; ++g) {
                        uint4 h0 = hb0[g], h1 = hb1[g];
                        a0 = dot2f(wA[4*g],   h0.x, a0); c0 = dot2f(wA[4*g+1], h0.y, c0);
                        a0 = dot2f(wA[4*g+2], h0.z, a0); c0 = dot2f(wA[4*g+3], h0.w, c0);
                        a1 = dot2f(wA[4*g],   h1.x, a1); c1 = dot2f(wA[4*g+1], h1.y, c1);
                        a1 = dot2f(wA[4*g+2], h1.z, a1); c1 = dot2f(wA[4*g+3], h1.w, c1);
                    }
                    #pragma unroll
                    for (int g = 0; g < 14; ++g) {
                        uint4 wa = ldsA[g * 512 + tid];
                        uint4 h0 = hb0[18 + g], h1 = hb1[18 + g];
                        a0 = dot2f(wa.x, h0.x, a0); c0 = dot2f(wa.y, h0.y, c0);
                        a0 = dot2f(wa.z, h0.z, a0); c0 = dot2f(wa.w, h0.w, c0);
                        a1 = dot2f(wa.x, h1.x, a1); c1 = dot2f(wa.y, h1.y, c1);
                        a1 = dot2f(wa.z, h1.z, a1); c1 = dot2f(wa.w, h1.w, c1);
                    }
                }
                pA[ch][0][w] = a0 + c0;
                pA[ch][1][w] = a1 + c1;
            }
            __syncthreads();  // B1

            // ---- reduce + quantize hint (role (b=ch, w)); prev-step FC finalize ----
            {
                float hi = pA[0][ch][w] + pA[1][ch][w];
                shint[ch][w] = hi;
                float am = fabsf(hi);
                #pragma unroll
                for (int o = 1; o < 64; o <<= 1) am = fmaxf(am, __shfl_xor(am, o));
                float qsc = 127.f / fmaxf(am, 1e-20f);
                int q = clampi8(__float2int_rn(hi * qsc));
                ((unsigned char*)hint8)[(ch << 8) + w] = (unsigned char)(q & 255);
                if ((w & 63) == 0) dqs[ch][w >> 6] = am * (1.f / 127.f);

                if (w == 0 && sidx > 0) {
                    int ps = sidx - 1, pi2 = ps >> 4, pt2 = ps & 15;
                    int pcol = (pi2 & 1) ? (15 - pt2) : pt2;
                    float l0 = bf0, l1 = bf1;
                    #pragma unroll
                    for (int vv = 0; vv < 8; ++vv) { l0 += fcp[ch][0][vv]; l1 += fcp[ch][1][vv]; }
                    float mx = fmaxf(l0, l1);
                    float lse = mx + logf(__expf(l0 - mx) + __expf(l1 - mx));
                    float xcur = sx[ch][(pi2 << 4) + pcol];
                    float mm = (1.f + xcur) * 0.5f;
                    float lp = (l0 - lse) * mm + (l1 - lse) * (1.f - mm);
                    if (pi2 == 0 && pcol == 0) lp = 1.f - mm;
                    lp_acc += lp;
                }
            }
            __syncthreads();  // B2

            // ---- Phase B + gates + h update + FC (fused, shfl_xor(32) cross-k) ----
            {
                const uint4* hq0 = ((const uint4*)hint8) + (sub << 3);       // batch0, k-half sub
                const uint4* hq1 = ((const uint4*)hint8) + 16 + (sub << 3);  // batch1
                int ra0=0,ra1=0,za0=0,za1=0,na0=0,na1=0;
                int rb0=0,rb1=0,zb0=0,zb1=0,nb0=0,nb1=0;
                #pragma unroll
                for (int gg = 0; gg < 4; ++gg) {
                    uint4 u0 = hq0[gg], u1 = hq1[gg];
                    const int k = gg << 2;
                    ra0 = sdot4(wB8[k],      u0.x, ra0); ra0 = sdot4(wB8[k+1],    u0.y, ra0);
                    ra0 = sdot4(wB8[k+2],    u0.z, ra0); ra0 = sdot4(wB8[k+3],    u0.w, ra0);
                    za0 = sdot4(wB8[32+k],   u0.x, za0); za0 = sdot4(wB8[32+k+1], u0.y, za0);
                    za0 = sdot4(wB8[32+k+2], u0.z, za0); za0 = sdot4(wB8[32+k+3], u0.w, za0);
                    na0 = sdot4(wB8[64+k],   u0.x, na0); na0 = sdot4(wB8[64+k+1], u0.y, na0);
                    na0 = sdot4(wB8[64+k+2], u0.z, na0); na0 = sdot4(wB8[64+k+3], u0.w, na0);
                    ra1 = sdot4(wB8[k],      u1.x, ra1); ra1 = sdot4(wB8[k+1],    u1.y, ra1);
                    ra1 = sdot4(wB8[k+2],    u1.z, ra1); ra1 = sdot4(wB8[k+3],    u1.w, ra1);
                    za1 = sdot4(wB8[32+k],   u1.x, za1); za1 = sdot4(wB8[32+k+1], u1.y, za1);
                    za1 = sdot4(wB8[32+k+2], u1.z, za1); za1 = sdot4(wB8[32+k+3], u1.w, za1);
                    na1 = sdot4(wB8[64+k],   u1.x, na1); na1 = sdot4(wB8[64+k+1], u1.y, na1);
                    na1 = sdot4(wB8[64+k+2], u1.z, na1); na1 = sdot4(wB8[64+k+3], u1.w, na1);
                }
                #pragma unroll
                for (int gg = 4; gg < 8; ++gg) {
                    uint4 u0 = hq0[gg], u1 = hq1[gg];
                    const int k = gg << 2;
                    rb0 = sdot4(wB8[k],      u0.x, rb0); rb0 = sdot4(wB8[k+1],    u0.y, rb0);
                    rb0 = sdot4(wB8[k+2],    u0.z, rb0); rb0 = sdot4(wB8[k+3],    u0.w, rb0);
                    zb0 = sdot4(wB8[32+k],   u0.x, zb0); zb0 = sdot4(wB8[32+k+1], u0.y, zb0);
                    zb0 = sdot4(wB8[32+k+2], u0.z, zb0); zb0 = sdot4(wB8[32+k+3], u0.w, zb0);
                    nb0 = sdot4(wB8[64+k],   u0.x, nb0); nb0 = sdot4(wB8[64+k+1], u0.y, nb0);
                    nb0 = sdot4(wB8[64+k+2], u0.z, nb0); nb0 = sdot4(wB8[64+k+3], u0.w, nb0);
                    rb1 = sdot4(wB8[k],      u1.x, rb1); rb1 = sdot4(wB8[k+1],    u1.y, rb1);
                    rb1 = sdot4(wB8[k+2],    u1.z, rb1); rb1 = sdot4(wB8[k+3],    u1.w, rb1);
                    zb1 = sdot4(wB8[32+k],   u1.x, zb1); zb1 = sdot4(wB8[32+k+1], u1.y, zb1);
                    zb1 = sdot4(wB8[32+k+2], u1.z, zb1); zb1 = sdot4(wB8[32+k+3], u1.w, zb1);
                    nb1 = sdot4(wB8[64+k],   u1.x, nb1); nb1 = sdot4(wB8[64+k+1], u1.y, nb1);
                    nb1 = sdot4(wB8[64+k+2], u1.z, nb1); nb1 = sdot4(wB8[64+k+3], u1.w, nb1);
                }
                const float d00 = dqs[0][2*sub], d01 = dqs[0][2*sub+1];
                const float d10 = dqs[1][2*sub], d11 = dqs[1][2*sub+1];
                float gr0 = (float)ra0 * d00 + (float)rb0 * d01;
                float gz0 = (float)za0 * d00 + (float)zb0 * d01;
                float gn0 = (float)na0 * d00 + (float)nb0 * d01;
                float gr1 = (float)ra1 * d10 + (float)rb1 * d11;
                float gz1 = (float)za1 * d10 + (float)zb1 * d11;
                float gn1 = (float)na1 * d10 + (float)nb1 * d11;
                gr0 += __shfl_xor(gr0, 32); gz0 += __shfl_xor(gz0, 32); gn0 += __shfl_xor(gn0, 32);
                gr1 += __shfl_xor(gr1, 32); gz1 += __shfl_xor(gz1, 32); gn1 += __shfl_xor(gn1, 32);

                const int bsel = sub;
                float GR = (bsel ? gr1 : gr0) * bsr[0];
                float GZ = (bsel ? gz1 : gz0) * bsr[1];
                float GN = (bsel ? gn1 : gn0) * bsr[2];
                float HI = shint[bsel][wB_];
                float xl = (t == 0) ? 0.f : sx[bsel][(i << 4) + col - dir];
                float xu = (i == 0) ? 0.f : sx[bsel][((i - 1) << 4) + col];
                float pu = (xl * xc0 + xu * xc1 + 1.f) * 0.5f;
                float rr_ = fsig(bA[0] * pu + bBi[0] + GR + bbh[0]);
                float zz = fsig(bA[1] * pu + bBi[1] + GZ + bbh[1]);
                float nn = ftanh_(bA[2] * pu + bBi[2] + rr_ * (GN + bbh[2]));
                float hn = (1.f - zz) * nn + zz * HI;
                unsigned short hu = f16b(hn);
                ((unsigned short*)h2pk)[(bsel << 8) + wB_] = hu;
                ((unsigned short*)hp2pk)[(bsel << 12) + (col << 8) + wB_] = hu;
                float s0 = hn * wfc0, s1 = hn * wfc1;
                #pragma unroll
                for (int o = 1; o < 32; o <<= 1) {
                    s0 += __shfl_xor(s0, o);
                    s1 += __shfl_xor(s1, o);
                }
                if (lr == 0) { fcp[bsel][0][v] = s0; fcp[bsel][1][v] = s1; }
            }
            __syncthreads();  // B3
        }
    }

    // ---- final step's FC finalize + output ----
    if (w == 0) {
        float l0 = bf0, l1 = bf1;
        #pragma unroll
        for (int vv = 0; vv < 8; ++vv) { l0 += fcp[ch][0][vv]; l1 += fcp[ch][1][vv]; }
        float mx = fmaxf(l0, l1);
        float lse = mx + logf(__expf(l0 - mx) + __expf(l1 - mx));
        float xcur = sx[ch][15 * 16 + 0];   // last step: i=15 (odd) -> col 0
        float mm = (1.f + xcur) * 0.5f;
        lp_acc += (l0 - lse) * mm + (l1 - lse) * (1.f - mm);
        out[b0 + ch] = lp_acc;
    }
}

extern "C" void kernel_launch(void* const* d_in, const int* in_sizes, int n_in,
                              void* d_out, int out_size, void* d_ws, size_t ws_size,
                              hipStream_t stream) {
    const float* x      = (const float*)d_in[0];
    const float* W_ih   = (const float*)d_in[1];
    const float* W_hh   = (const float*)d_in[2];
    const float* b_ih   = (const float*)d_in[3];
    const float* b_hh   = (const float*)d_in[4];
    const float* W_fc   = (const float*)d_in[5];
    const float* b_fc   = (const float*)d_in[6];
    const float* W_hcat = (const float*)d_in[7];
    const float* W_xcat = (const float*)d_in[8];
    float* out = (float*)d_out;
    float* ws  = (float*)d_ws;

    gru2d_prep1<<<768, 64, 0, stream>>>(W_hh, ws);
    gru2d_prep2<<<451, 256, 0, stream>>>(W_ih, W_hh, b_ih, W_hcat, ws);
    gru2d_main<<<256, 512, 0, stream>>>(x, b_hh, W_fc, b_fc, W_xcat, ws, out);
}

// Round 9
// 945.983 us; speedup vs baseline: 4.6160x; 1.0288x over previous
//
#include <hip/hip_runtime.h>
#include <math.h>

#define LL 16
#define WD 256
#define G3 768

// ws layout (u32 units)
#define OFF_A8  0        // 32768 u32 : W_hcat i8 (16 uint4/thread, per-row scales)
#define OFF_B8  32768    // 49152 u32 : W_hh int8 (24 uint4/thread)
#define OFF_SRB 81920    // 768 f32 : per-row scale of W_hh (max|row|/127)
#define OFF_SRA 82688    // 256 f32 : per-row scale of W_hcat
#define OFF_GA  82944    // 768 f32 : W_ih[:,0]-W_ih[:,1]
#define OFF_GBI 83712    // 768 f32 : W_ih[:,1]+b_ih

__device__ __forceinline__ int sdot4(unsigned a, unsigned b, int acc) {
#if __has_builtin(__builtin_amdgcn_sdot4)
    return __builtin_amdgcn_sdot4((int)a, (int)b, acc, false);
#else
    int s = acc;
    #pragma unroll
    for (int r = 0; r < 4; ++r)
        s += (int)(signed char)(a >> (8 * r)) * (int)(signed char)(b >> (8 * r));
    return s;
#endif
}
__device__ __forceinline__ float fsig(float v) { return 1.f / (1.f + __expf(-v)); }
__device__ __forceinline__ float ftanh_(float v) {
    v = fminf(fmaxf(v, -15.f), 15.f);
    float e = __expf(-2.f * v);
    return (1.f - e) / (1.f + e);
}
__device__ __forceinline__ int clampi8(int q) {
    return q > 127 ? 127 : (q < -127 ? -127 : q);
}

// per-row max-abs scales: rows 0..767 = W_hh (256-wide), 768..1023 = W_hcat (512-wide)
__global__ __launch_bounds__(64)
void gru2d_prep1(const float* __restrict__ W_hh, const float* __restrict__ W_hcat,
                 float* __restrict__ ws) {
    int row = blockIdx.x, lane = threadIdx.x;
    float s = 0.f;
    if (row < 768) {
        for (int k = lane; k < 256; k += 64) s = fmaxf(s, fabsf(W_hh[row * 256 + k]));
    } else {
        int r = row - 768;
        for (int k = lane; k < 512; k += 64) s = fmaxf(s, fabsf(W_hcat[r * 512 + k]));
    }
    #pragma unroll
    for (int o = 32; o > 0; o >>= 1) s = fmaxf(s, __shfl_down(s, o));
    if (lane == 0) {
        float sc = (s > 0.f) ? s * (1.f / 127.f) : 1.f;
        if (row < 768) ws[OFF_SRB + row] = sc;
        else           ws[OFF_SRA + (row - 768)] = sc;
    }
}

// A8 (Phase-A role thread t: w=t&255, ch=t>>8): row w of [Wh_l|Wh_u] as i8,
//   concat-k half [ch*256,+256) -> 64 u32 j: wsu[OFF_A8 + (g4*512+t)*4+r], j=g4*4+r,
//   u32 j holds k = ch*256 + 4j .. +3.
// B8 (Phase-B role thread t: v=t>>6, l=t&63, wB=v*32+(l&31), chB=l>>5):
//   gate rows {wB,256+wB,512+wB} of W_hh as i8, k in [chB*128,+128): wB8[gate*32+q].
__global__ __launch_bounds__(256)
void gru2d_prep2(const float* __restrict__ W_ih, const float* __restrict__ W_hh,
                 const float* __restrict__ b_ih, const float* __restrict__ W_hcat,
                 float* __restrict__ ws) {
    unsigned* __restrict__ wsu = (unsigned*)ws;
    int m = blockIdx.x * 256 + threadIdx.x;
    if (m < 32768) {
        int g4 = m >> 11, t = (m >> 2) & 511, r = m & 3;
        int j = g4 * 4 + r;
        int w = t & 255, ch = t >> 8;
        float inv = 1.f / ws[OFF_SRA + w];
        int base = w * 512 + ch * 256 + 4 * j;
        unsigned pk = 0;
        #pragma unroll
        for (int bb = 0; bb < 4; ++bb) {
            int qv = clampi8(__float2int_rn(W_hcat[base + bb] * inv));
            pk |= ((unsigned)(qv & 255)) << (8 * bb);
        }
        wsu[OFF_A8 + m] = pk;
    } else if (m < 81920) {
        int mm = m - 32768;
        int g4 = mm >> 11, t = (mm >> 2) & 511, rr = mm & 3;
        int ql = g4 * 4 + rr;
        int gate = ql >> 5, q = ql & 31;
        int v = t >> 6, l = t & 63;
        int wB_ = v * 32 + (l & 31), chB = l >> 5;
        int row = gate * 256 + wB_;
        float inv = 1.f / ws[OFF_SRB + row];
        int kb = row * 256 + chB * 128 + 4 * q;
        unsigned pk = 0;
        #pragma unroll
        for (int bb = 0; bb < 4; ++bb) {
            int qv = clampi8(__float2int_rn(W_hh[kb + bb] * inv));
            pk |= ((unsigned)(qv & 255)) << (8 * bb);
        }
        wsu[OFF_B8 + mm] = pk;
    } else if (m < 82688) {
        int e = m - 81920;
        float w0 = W_ih[2 * e], w1 = W_ih[2 * e + 1];
        ws[OFF_GA + e] = w0 - w1;
        ws[OFF_GBI + e] = w1 + b_ih[e];
    }
}

// 512 threads (2 waves/SIMD), 1 block/CU, 2 batches/block.
// All weights i8 in registers (160 u32/thread, per-step-pinned). h stored as i8
// with per-32-row dynamic scales; hint f32 (shint) preserved for the z-mix.
// 3 barriers/step.
__global__ __launch_bounds__(512, 2)
void gru2d_main(const float* __restrict__ x, const float* __restrict__ b_hh,
                const float* __restrict__ W_fc, const float* __restrict__ b_fc,
                const float* __restrict__ W_xcat, const float* __restrict__ ws,
                float* __restrict__ out) {
    __shared__ __attribute__((aligned(16))) unsigned h8[2][64];         // i8 h_left
    __shared__ __attribute__((aligned(16))) unsigned hp8[2][LL][64];    // i8 prev-row h
    __shared__ float hs8[2][8];                                         // h chunk scales
    __shared__ float hps8[2][LL][8];
    __shared__ __attribute__((aligned(16))) float pA[2][2][256];
    __shared__ __attribute__((aligned(16))) float shint[2][256];
    __shared__ __attribute__((aligned(16))) unsigned hint8q[2][64];
    __shared__ float dqs[2][4];
    __shared__ float fcp[2][2][8];
    __shared__ float sx[2][256];

    const int tid = threadIdx.x;
    const int w = tid & 255;
    const int ch = tid >> 8;                 // Phase A / reduce role (wave-uniform)
    const int v = tid >> 6, l = tid & 63;
    const int lr = l & 31, sub = l >> 5;
    const int wB_ = (v << 5) + lr;           // Phase B / gates / FC role
    const int b0 = blockIdx.x * 2;
    const unsigned* __restrict__ wsu = (const unsigned*)ws;

    // ---- persistent i8 weights -> registers (coalesced uint4) ----
    unsigned wA8[64], wB8[96];
    #pragma unroll
    for (int g = 0; g < 16; ++g) {
        uint4 q = ((const uint4*)(wsu + OFF_A8))[g * 512 + tid];
        wA8[4*g] = q.x; wA8[4*g+1] = q.y; wA8[4*g+2] = q.z; wA8[4*g+3] = q.w;
    }
    #pragma unroll
    for (int g = 0; g < 24; ++g) {
        uint4 q = ((const uint4*)(wsu + OFF_B8))[g * 512 + tid];
        wB8[4*g] = q.x; wB8[4*g+1] = q.y; wB8[4*g+2] = q.z; wB8[4*g+3] = q.w;
    }

    const float ascale = ws[OFF_SRA + w];    // Phase-A row scale
    float bA[3], bBi[3], bbh[3], bsr[3];
    #pragma unroll
    for (int g = 0; g < 3; ++g) {
        bA[g]  = ws[OFF_GA + (g << 8) + wB_];
        bBi[g] = ws[OFF_GBI + (g << 8) + wB_];
        bbh[g] = b_hh[(g << 8) + wB_];
        bsr[g] = ws[OFF_SRB + (g << 8) + wB_];
    }
    const float wfc0 = W_fc[wB_], wfc1 = W_fc[256 + wB_];
    sx[ch][w] = x[(b0 + ch) * 256 + w];
    {   // zero hp8 + hps8 (hps8 must be finite: 0*NaN would poison)
        unsigned* hp = (unsigned*)hp8;
        #pragma unroll
        for (int g = 0; g < 4; ++g) hp[g * 512 + tid] = 0u;
        if (tid < 256) ((float*)hps8)[tid] = 0.f;
    }
    const float xc0 = W_xcat[0], xc1 = W_xcat[1];
    const float bf0 = b_fc[0], bf1 = b_fc[1];
    float lp_acc = 0.f;
    __syncthreads();

    for (int i = 0; i < LL; ++i) {
        const int odd = i & 1;
        const int dir = odd ? -1 : 1;
        const int c0g = odd ? (LL - 1) : 0;
        for (int t = 0; t < LL; ++t) {
            const int col = c0g + dir * t;
            const int sidx = (i << 4) + t;

            // per-step pins: USE+DEF each iteration -> spilling would cost a
            // reload per step -> allocator keeps weights resident (R5/R8-proven)
            #pragma unroll
            for (int g = 0; g < 16; ++g)
                asm volatile("" : "+v"(wA8[4*g]), "+v"(wA8[4*g+1]), "+v"(wA8[4*g+2]), "+v"(wA8[4*g+3]));
            #pragma unroll
            for (int g = 0; g < 24; ++g)
                asm volatile("" : "+v"(wB8[4*g]), "+v"(wB8[4*g+1]), "+v"(wB8[4*g+2]), "+v"(wB8[4*g+3]));

            // ---- Phase A: hint partials, row w, k-half ch (i8 x i8) ----
            {
                const uint4* Hb0;
                const uint4* Hb1;
                const float* sc0;
                const float* sc1;
                if (ch == 0) {
                    Hb0 = (const uint4*)h8[0];       Hb1 = (const uint4*)h8[1];
                    sc0 = hs8[0];                     sc1 = hs8[1];
                } else {
                    Hb0 = (const uint4*)hp8[0][col]; Hb1 = (const uint4*)hp8[1][col];
                    sc0 = hps8[0][col];               sc1 = hps8[1][col];
                }
                float fa0 = 0.f, fa1 = 0.f;
                if (!(ch == 0 && t == 0)) {
                    #pragma unroll
                    for (int c = 0; c < 8; ++c) {
                        uint4 u0a = Hb0[2*c], u0b = Hb0[2*c+1];
                        uint4 u1a = Hb1[2*c], u1b = Hb1[2*c+1];
                        int a0 = 0, a1 = 0;
                        const int kk = c << 3;
                        a0 = sdot4(wA8[kk],   u0a.x, a0); a0 = sdot4(wA8[kk+1], u0a.y, a0);
                        a0 = sdot4(wA8[kk+2], u0a.z, a0); a0 = sdot4(wA8[kk+3], u0a.w, a0);
                        a0 = sdot4(wA8[kk+4], u0b.x, a0); a0 = sdot4(wA8[kk+5], u0b.y, a0);
                        a0 = sdot4(wA8[kk+6], u0b.z, a0); a0 = sdot4(wA8[kk+7], u0b.w, a0);
                        a1 = sdot4(wA8[kk],   u1a.x, a1); a1 = sdot4(wA8[kk+1], u1a.y, a1);
                        a1 = sdot4(wA8[kk+2], u1a.z, a1); a1 = sdot4(wA8[kk+3], u1a.w, a1);
                        a1 = sdot4(wA8[kk+4], u1b.x, a1); a1 = sdot4(wA8[kk+5], u1b.y, a1);
                        a1 = sdot4(wA8[kk+6], u1b.z, a1); a1 = sdot4(wA8[kk+7], u1b.w, a1);
                        fa0 += (float)a0 * sc0[c];
                        fa1 += (float)a1 * sc1[c];
                    }
                    fa0 *= ascale;
                    fa1 *= ascale;
                }
                pA[ch][0][w] = fa0;
                pA[ch][1][w] = fa1;
            }
            __syncthreads();  // B1

            // ---- reduce + quantize hint (role (b=ch, w)); prev-step FC finalize ----
            {
                float hi = pA[0][ch][w] + pA[1][ch][w];
                shint[ch][w] = hi;
                float am = fabsf(hi);
                #pragma unroll
                for (int o = 1; o < 64; o <<= 1) am = fmaxf(am, __shfl_xor(am, o));
                float qsc = 127.f / fmaxf(am, 1e-20f);
                int q = clampi8(__float2int_rn(hi * qsc));
                ((unsigned char*)hint8q)[(ch << 8) + w] = (unsigned char)(q & 255);
                if ((w & 63) == 0) dqs[ch][w >> 6] = am * (1.f / 127.f);

                if (w == 0 && sidx > 0) {
                    int ps = sidx - 1, pi2 = ps >> 4, pt2 = ps & 15;
                    int pcol = (pi2 & 1) ? (15 - pt2) : pt2;
                    float l0 = bf0, l1 = bf1;
                    #pragma unroll
                    for (int vv = 0; vv < 8; ++vv) { l0 += fcp[ch][0][vv]; l1 += fcp[ch][1][vv]; }
                    float mx = fmaxf(l0, l1);
                    float lse = mx + logf(__expf(l0 - mx) + __expf(l1 - mx));
                    float xcur = sx[ch][(pi2 << 4) + pcol];
                    float mm = (1.f + xcur) * 0.5f;
                    float lp = (l0 - lse) * mm + (l1 - lse) * (1.f - mm);
                    if (pi2 == 0 && pcol == 0) lp = 1.f - mm;
                    lp_acc += lp;
                }
            }
            __syncthreads();  // B2

            // ---- Phase B + gates + h update (i8 quant) + FC ----
            {
                const uint4* hq0 = ((const uint4*)hint8q) + (sub << 3);       // batch0, k-half sub
                const uint4* hq1 = ((const uint4*)hint8q) + 16 + (sub << 3);  // batch1
                int ra0=0,ra1=0,za0=0,za1=0,na0=0,na1=0;
                int rb0=0,rb1=0,zb0=0,zb1=0,nb0=0,nb1=0;
                #pragma unroll
                for (int gg = 0; gg < 4; ++gg) {
                    uint4 u0 = hq0[gg], u1 = hq1[gg];
                    const int k = gg << 2;
                    ra0 = sdot4(wB8[k],      u0.x, ra0); ra0 = sdot4(wB8[k+1],    u0.y, ra0);
                    ra0 = sdot4(wB8[k+2],    u0.z, ra0); ra0 = sdot4(wB8[k+3],    u0.w, ra0);
                    za0 = sdot4(wB8[32+k],   u0.x, za0); za0 = sdot4(wB8[32+k+1], u0.y, za0);
                    za0 = sdot4(wB8[32+k+2], u0.z, za0); za0 = sdot4(wB8[32+k+3], u0.w, za0);
                    na0 = sdot4(wB8[64+k],   u0.x, na0); na0 = sdot4(wB8[64+k+1], u0.y, na0);
                    na0 = sdot4(wB8[64+k+2], u0.z, na0); na0 = sdot4(wB8[64+k+3], u0.w, na0);
                    ra1 = sdot4(wB8[k],      u1.x, ra1); ra1 = sdot4(wB8[k+1],    u1.y, ra1);
                    ra1 = sdot4(wB8[k+2],    u1.z, ra1); ra1 = sdot4(wB8[k+3],    u1.w, ra1);
                    za1 = sdot4(wB8[32+k],   u1.x, za1); za1 = sdot4(wB8[32+k+1], u1.y, za1);
                    za1 = sdot4(wB8[32+k+2], u1.z, za1); za1 = sdot4(wB8[32+k+3], u1.w, za1);
                    na1 = sdot4(wB8[64+k],   u1.x, na1); na1 = sdot4(wB8[64+k+1], u1.y, na1);
                    na1 = sdot4(wB8[64+k+2], u1.z, na1); na1 = sdot4(wB8[64+k+3], u1.w, na1);
                }
                #pragma unroll
                for (int gg = 4; gg < 8; ++gg) {
                    uint4 u0 = hq0[gg], u1 = hq1[gg];
                    const int k = gg << 2;
                    rb0 = sdot4(wB8[k],      u0.x, rb0); rb0 = sdot4(wB8[k+1],    u0.y, rb0);
                    rb0 = sdot4(wB8[k+2],    u0.z, rb0); rb0 = sdot4(wB8[k+3],    u0.w, rb0);
                    zb0 = sdot4(wB8[32+k],   u0.x, zb0); zb0 = sdot4(wB8[32+k+1], u0.y, zb0);
                    zb0 = sdot4(wB8[32+k+2], u0.z, zb0); zb0 = sdot4(wB8[32+k+3], u0.w, zb0);
                    nb0 = sdot4(wB8[64+k],   u0.x, nb0); nb0 = sdot4(wB8[64+k+1], u0.y, nb0);
                    nb0 = sdot4(wB8[64+k+2], u0.z, nb0); nb0 = sdot4(wB8[64+k+3], u0.w, nb0);
                    rb1 = sdot4(wB8[k],      u1.x, rb1); rb1 = sdot4(wB8[k+1],    u1.y, rb1);
                    rb1 = sdot4(wB8[k+2],    u1.z, rb1); rb1 = sdot4(wB8[k+3],    u1.w, rb1);
                    zb1 = sdot4(wB8[32+k],   u1.x, zb1); zb1 = sdot4(wB8[32+k+1], u1.y, zb1);
                    zb1 = sdot4(wB8[32+k+2], u1.z, zb1); zb1 = sdot4(wB8[32+k+3], u1.w, zb1);
                    nb1 = sdot4(wB8[64+k],   u1.x, nb1); nb1 = sdot4(wB8[64+k+1], u1.y, nb1);
                    nb1 = sdot4(wB8[64+k+2], u1.z, nb1); nb1 = sdot4(wB8[64+k+3], u1.w, nb1);
                }
                const float d00 = dqs[0][2*sub], d01 = dqs[0][2*sub+1];
                const float d10 = dqs[1][2*sub], d11 = dqs[1][2*sub+1];
                float gr0 = (float)ra0 * d00 + (float)rb0 * d01;
                float gz0 = (float)za0 * d00 + (float)zb0 * d01;
                float gn0 = (float)na0 * d00 + (float)nb0 * d01;
                float gr1 = (float)ra1 * d10 + (float)rb1 * d11;
                float gz1 = (float)za1 * d10 + (float)zb1 * d11;
                float gn1 = (float)na1 * d10 + (float)nb1 * d11;
                gr0 += __shfl_xor(gr0, 32); gz0 += __shfl_xor(gz0, 32); gn0 += __shfl_xor(gn0, 32);
                gr1 += __shfl_xor(gr1, 32); gz1 += __shfl_xor(gz1, 32); gn1 += __shfl_xor(gn1, 32);

                const int bsel = sub;
                float GR = (bsel ? gr1 : gr0) * bsr[0];
                float GZ = (bsel ? gz1 : gz0) * bsr[1];
                float GN = (bsel ? gn1 : gn0) * bsr[2];
                float HI = shint[bsel][wB_];
                float xl = (t == 0) ? 0.f : sx[bsel][(i << 4) + col - dir];
                float xu = (i == 0) ? 0.f : sx[bsel][((i - 1) << 4) + col];
                float pu = (xl * xc0 + xu * xc1 + 1.f) * 0.5f;
                float rr_ = fsig(bA[0] * pu + bBi[0] + GR + bbh[0]);
                float zz = fsig(bA[1] * pu + bBi[1] + GZ + bbh[1]);
                float nn = ftanh_(bA[2] * pu + bBi[2] + rr_ * (GN + bbh[2]));
                float hn = (1.f - zz) * nn + zz * HI;

                // ---- quantize h -> i8 (per-32-row chunk scale, within lane-half) ----
                float am = fabsf(hn);
                #pragma unroll
                for (int o = 1; o < 32; o <<= 1) am = fmaxf(am, __shfl_xor(am, o));
                float qs = 127.f / fmaxf(am, 1e-20f);
                unsigned q = (unsigned)(clampi8(__float2int_rn(hn * qs)) & 255);
                unsigned q1 = __shfl_down(q, 1);
                unsigned q2 = __shfl_down(q, 2);
                unsigned q3 = __shfl_down(q, 3);
                if ((lr & 3) == 0) {
                    unsigned pk = q | (q1 << 8) | (q2 << 16) | (q3 << 24);
                    int idx = (v << 3) + (lr >> 2);
                    h8[bsel][idx] = pk;
                    hp8[bsel][col][idx] = pk;
                }
                if (lr == 0) {
                    float hsc = am * (1.f / 127.f);
                    hs8[bsel][v] = hsc;
                    hps8[bsel][col][v] = hsc;
                }

                float s0 = hn * wfc0, s1 = hn * wfc1;
                #pragma unroll
                for (int o = 1; o < 32; o <<= 1) {
                    s0 += __shfl_xor(s0, o);
                    s1 += __shfl_xor(s1, o);
                }
                if (lr == 0) { fcp[bsel][0][v] = s0; fcp[bsel][1][v] = s1; }
            }
            __syncthreads();  // B3
        }
    }

    // ---- final step's FC finalize + output ----
    if (w == 0) {
        float l0 = bf0, l1 = bf1;
        #pragma unroll
        for (int vv = 0; vv < 8; ++vv) { l0 += fcp[ch][0][vv]; l1 += fcp[ch][1][vv]; }
        float mx = fmaxf(l0, l1);
        float lse = mx + logf(__expf(l0 - mx) + __expf(l1 - mx));
        float xcur = sx[ch][15 * 16 + 0];   // last step: i=15 (odd) -> col 0
        float mm = (1.f + xcur) * 0.5f;
        lp_acc += (l0 - lse) * mm + (l1 - lse) * (1.f - mm);
        out[b0 + ch] = lp_acc;
    }
}

extern "C" void kernel_launch(void* const* d_in, const int* in_sizes, int n_in,
                              void* d_out, int out_size, void* d_ws, size_t ws_size,
                              hipStream_t stream) {
    const float* x      = (const float*)d_in[0];
    const float* W_ih   = (const float*)d_in[1];
    const float* W_hh   = (const float*)d_in[2];
    const float* b_ih   = (const float*)d_in[3];
    const float* b_hh   = (const float*)d_in[4];
    const float* W_fc   = (const float*)d_in[5];
    const float* b_fc   = (const float*)d_in[6];
    const float* W_hcat = (const float*)d_in[7];
    const float* W_xcat = (const float*)d_in[8];
    float* out = (float*)d_out;
    float* ws  = (float*)d_ws;

    gru2d_prep1<<<1024, 64, 0, stream>>>(W_hh, W_hcat, ws);
    gru2d_prep2<<<323, 256, 0, stream>>>(W_ih, W_hh, b_ih, W_hcat, ws);
    gru2d_main<<<256, 512, 0, stream>>>(x, b_hh, W_fc, b_fc, W_xcat, ws, out);
}

// Round 10
// 899.385 us; speedup vs baseline: 4.8552x; 1.0518x over previous
//
#include <hip/hip_runtime.h>
#include <math.h>

#define LL 16
#define WD 256
#define G3 768

// ws layout (u32 units)
#define OFF_A8  0        // 32768 u32 : W_hcat i8 (16 uint4/thread)
#define OFF_B8  32768    // 49152 u32 : W_hh i8 (24 uint4/thread)
#define OFF_SRB 81920    // 768 f32 : per-row scale of W_hh
#define OFF_SRA 82688    // 256 f32 : per-row scale of W_hcat
#define OFF_GA  82944    // 768 f32 : W_ih[:,0]-W_ih[:,1]
#define OFF_GBI 83712    // 768 f32 : W_ih[:,1]+b_ih

__device__ __forceinline__ int sdot4(unsigned a, unsigned b, int acc) {
#if __has_builtin(__builtin_amdgcn_sdot4)
    return __builtin_amdgcn_sdot4((int)a, (int)b, acc, false);
#else
    int s = acc;
    #pragma unroll
    for (int r = 0; r < 4; ++r)
        s += (int)(signed char)(a >> (8 * r)) * (int)(signed char)(b >> (8 * r));
    return s;
#endif
}
__device__ __forceinline__ float fsig(float v) { return 1.f / (1.f + __expf(-v)); }
__device__ __forceinline__ float ftanh_(float v) {
    v = fminf(fmaxf(v, -15.f), 15.f);
    float e = __expf(-2.f * v);
    return (1.f - e) / (1.f + e);
}
__device__ __forceinline__ int clampi8(int q) {
    return q > 127 ? 127 : (q < -127 ? -127 : q);
}

// per-row max-abs scales: rows 0..767 = W_hh (256-wide), 768..1023 = W_hcat (512-wide)
__global__ __launch_bounds__(64)
void gru2d_prep1(const float* __restrict__ W_hh, const float* __restrict__ W_hcat,
                 float* __restrict__ ws) {
    int row = blockIdx.x, lane = threadIdx.x;
    float s = 0.f;
    if (row < 768) {
        for (int k = lane; k < 256; k += 64) s = fmaxf(s, fabsf(W_hh[row * 256 + k]));
    } else {
        int r = row - 768;
        for (int k = lane; k < 512; k += 64) s = fmaxf(s, fabsf(W_hcat[r * 512 + k]));
    }
    #pragma unroll
    for (int o = 32; o > 0; o >>= 1) s = fmaxf(s, __shfl_down(s, o));
    if (lane == 0) {
        float sc = (s > 0.f) ? s * (1.f / 127.f) : 1.f;
        if (row < 768) ws[OFF_SRB + row] = sc;
        else           ws[OFF_SRA + (row - 768)] = sc;
    }
}

// Main-thread role (t: v=t>>6, l=t&63, lr=l&31, sub=l>>5, w=v*32+lr):
// A8: row w of [Wh_l|Wh_u] as i8, k-half [sub*256,+256) -> 64 u32 j:
//     wsu[OFF_A8 + (g4*512+t)*4+r], j=g4*4+r, u32 j holds k = sub*256+4j..+3.
// B8: gate rows {w,256+w,512+w} of W_hh as i8, k in [sub*128,+128): wB8[gate*32+q].
__global__ __launch_bounds__(256)
void gru2d_prep2(const float* __restrict__ W_ih, const float* __restrict__ W_hh,
                 const float* __restrict__ b_ih, const float* __restrict__ W_hcat,
                 float* __restrict__ ws) {
    unsigned* __restrict__ wsu = (unsigned*)ws;
    int m = blockIdx.x * 256 + threadIdx.x;
    if (m < 32768) {
        int g4 = m >> 11, t = (m >> 2) & 511, r = m & 3;
        int j = g4 * 4 + r;
        int v = t >> 6, l = t & 63;
        int w = v * 32 + (l & 31), kh = l >> 5;
        float inv = 1.f / ws[OFF_SRA + w];
        int base = w * 512 + kh * 256 + 4 * j;
        unsigned pk = 0;
        #pragma unroll
        for (int bb = 0; bb < 4; ++bb) {
            int qv = clampi8(__float2int_rn(W_hcat[base + bb] * inv));
            pk |= ((unsigned)(qv & 255)) << (8 * bb);
        }
        wsu[OFF_A8 + m] = pk;
    } else if (m < 81920) {
        int mm = m - 32768;
        int g4 = mm >> 11, t = (mm >> 2) & 511, rr = mm & 3;
        int ql = g4 * 4 + rr;
        int gate = ql >> 5, q = ql & 31;
        int v = t >> 6, l = t & 63;
        int w = v * 32 + (l & 31), kh = l >> 5;
        int row = gate * 256 + w;
        float inv = 1.f / ws[OFF_SRB + row];
        int kb = row * 256 + kh * 128 + 4 * q;
        unsigned pk = 0;
        #pragma unroll
        for (int bb = 0; bb < 4; ++bb) {
            int qv = clampi8(__float2int_rn(W_hh[kb + bb] * inv));
            pk |= ((unsigned)(qv & 255)) << (8 * bb);
        }
        wsu[OFF_B8 + mm] = pk;
    } else if (m < 82688) {
        int e = m - 81920;
        float w0 = W_ih[2 * e], w1 = W_ih[2 * e + 1];
        ws[OFF_GA + e] = w0 - w1;
        ws[OFF_GBI + e] = w1 + b_ih[e];
    }
}

// 512 threads (2 waves/SIMD), 1 block/CU, 2 batches/block.
// TWO phases, TWO barriers per step. Phase A: k-split intra-wave (sub),
// cross-k via shfl_xor(32); hint stays in-register for the gates (row match).
__global__ __launch_bounds__(512, 2)
void gru2d_main(const float* __restrict__ x, const float* __restrict__ b_hh,
                const float* __restrict__ W_fc, const float* __restrict__ b_fc,
                const float* __restrict__ W_xcat, const float* __restrict__ ws,
                float* __restrict__ out) {
    __shared__ __attribute__((aligned(16))) unsigned h8[2][64];       // i8 h_left
    __shared__ __attribute__((aligned(16))) unsigned hp8[2][LL][64];  // i8 prev-row h
    __shared__ float hs8[2][8];                                       // h chunk scales (32-row)
    __shared__ float hps8[2][LL][8];
    __shared__ __attribute__((aligned(16))) unsigned hint8q[2][64];   // i8 hint
    __shared__ float dqs[2][8];                                       // hint chunk scales (32-wide)
    __shared__ float fcp[2][2][8];
    __shared__ float sx[2][256];

    const int tid = threadIdx.x;
    const int v = tid >> 6, l = tid & 63;
    const int lr = l & 31, sub = l >> 5;
    const int w = (v << 5) + lr;            // row for A-output, B rows, gates, FC
    const int b0 = blockIdx.x * 2;
    const unsigned* __restrict__ wsu = (const unsigned*)ws;

    // ---- persistent i8 weights -> registers (coalesced uint4) ----
    unsigned wA8[64], wB8[96];
    #pragma unroll
    for (int g = 0; g < 16; ++g) {
        uint4 q = ((const uint4*)(wsu + OFF_A8))[g * 512 + tid];
        wA8[4*g] = q.x; wA8[4*g+1] = q.y; wA8[4*g+2] = q.z; wA8[4*g+3] = q.w;
    }
    #pragma unroll
    for (int g = 0; g < 24; ++g) {
        uint4 q = ((const uint4*)(wsu + OFF_B8))[g * 512 + tid];
        wB8[4*g] = q.x; wB8[4*g+1] = q.y; wB8[4*g+2] = q.z; wB8[4*g+3] = q.w;
    }

    const float ascale = ws[OFF_SRA + w];
    float bA[3], bBi[3], bbh[3], bsr[3];
    #pragma unroll
    for (int g = 0; g < 3; ++g) {
        bA[g]  = ws[OFF_GA + (g << 8) + w];
        bBi[g] = ws[OFF_GBI + (g << 8) + w];
        bbh[g] = b_hh[(g << 8) + w];
        bsr[g] = ws[OFF_SRB + (g << 8) + w];
    }
    const float wfc0 = W_fc[w], wfc1 = W_fc[256 + w];
    sx[tid >> 8][tid & 255] = x[(b0 + (tid >> 8)) * 256 + (tid & 255)];
    {
        unsigned* hp = (unsigned*)hp8;
        #pragma unroll
        for (int g = 0; g < 4; ++g) hp[g * 512 + tid] = 0u;
        if (tid < 256) ((float*)hps8)[tid] = 0.f;
    }
    const float xc0 = W_xcat[0], xc1 = W_xcat[1];
    const float bf0 = b_fc[0], bf1 = b_fc[1];
    float lp_acc = 0.f;
    __syncthreads();

    for (int i = 0; i < LL; ++i) {
        const int odd = i & 1;
        const int dir = odd ? -1 : 1;
        const int c0g = odd ? (LL - 1) : 0;
        for (int t = 0; t < LL; ++t) {
            const int col = c0g + dir * t;
            const int sidx = (i << 4) + t;

            // per-step pins: USE+DEF each iteration -> no remat, no spill (proven)
            #pragma unroll
            for (int g = 0; g < 16; ++g)
                asm volatile("" : "+v"(wA8[4*g]), "+v"(wA8[4*g+1]), "+v"(wA8[4*g+2]), "+v"(wA8[4*g+3]));
            #pragma unroll
            for (int g = 0; g < 24; ++g)
                asm volatile("" : "+v"(wB8[4*g]), "+v"(wB8[4*g+1]), "+v"(wB8[4*g+2]), "+v"(wB8[4*g+3]));

            // ---- prev-step FC finalize (2 lanes; overlaps other waves' Phase A) ----
            if ((tid == 0 || tid == 256) && sidx > 0) {
                const int b = tid >> 8;
                int ps = sidx - 1, pi2 = ps >> 4, pt2 = ps & 15;
                int pcol = (pi2 & 1) ? (15 - pt2) : pt2;
                float l0 = bf0, l1 = bf1;
                #pragma unroll
                for (int vv = 0; vv < 8; ++vv) { l0 += fcp[b][0][vv]; l1 += fcp[b][1][vv]; }
                float mx = fmaxf(l0, l1);
                float lse = mx + logf(__expf(l0 - mx) + __expf(l1 - mx));
                float xcur = sx[b][(pi2 << 4) + pcol];
                float mm = (1.f + xcur) * 0.5f;
                float lp = (l0 - lse) * mm + (l1 - lse) * (1.f - mm);
                if (pi2 == 0 && pcol == 0) lp = 1.f - mm;
                lp_acc += lp;
            }

            // ---- Phase A: full hint for (w, both batches); k-half = sub ----
            float hi_sel;     // hint[bsel=sub][w] - stays in register for gates
            {
                float fa0 = 0.f, fa1 = 0.f;
                if (!(sub == 0 && t == 0)) {   // sub 0 = h_left (0 at row start)
                    const uint4* H0 = sub ? (const uint4*)hp8[0][col] : (const uint4*)h8[0];
                    const uint4* H1 = sub ? (const uint4*)hp8[1][col] : (const uint4*)h8[1];
                    const float* s0p = sub ? hps8[0][col] : hs8[0];
                    const float* s1p = sub ? hps8[1][col] : hs8[1];
                    #pragma unroll
                    for (int c = 0; c < 8; ++c) {
                        uint4 ua0 = H0[2*c], ub0 = H0[2*c+1];
                        uint4 ua1 = H1[2*c], ub1 = H1[2*c+1];
                        const int kk = c << 3;
                        int a0 = 0, a1 = 0;
                        a0 = sdot4(wA8[kk],   ua0.x, a0); a0 = sdot4(wA8[kk+1], ua0.y, a0);
                        a0 = sdot4(wA8[kk+2], ua0.z, a0); a0 = sdot4(wA8[kk+3], ua0.w, a0);
                        a0 = sdot4(wA8[kk+4], ub0.x, a0); a0 = sdot4(wA8[kk+5], ub0.y, a0);
                        a0 = sdot4(wA8[kk+6], ub0.z, a0); a0 = sdot4(wA8[kk+7], ub0.w, a0);
                        a1 = sdot4(wA8[kk],   ua1.x, a1); a1 = sdot4(wA8[kk+1], ua1.y, a1);
                        a1 = sdot4(wA8[kk+2], ua1.z, a1); a1 = sdot4(wA8[kk+3], ua1.w, a1);
                        a1 = sdot4(wA8[kk+4], ub1.x, a1); a1 = sdot4(wA8[kk+5], ub1.y, a1);
                        a1 = sdot4(wA8[kk+6], ub1.z, a1); a1 = sdot4(wA8[kk+7], ub1.w, a1);
                        fa0 += (float)a0 * s0p[c];
                        fa1 += (float)a1 * s1p[c];
                    }
                    fa0 *= ascale;
                    fa1 *= ascale;
                }
                fa0 += __shfl_xor(fa0, 32);    // cross-k: both halves get full sum
                fa1 += __shfl_xor(fa1, 32);
                // select batch BEFORE the max chain: half sub quantizes batch sub
                hi_sel = sub ? fa1 : fa0;
                float am = fabsf(hi_sel);
                #pragma unroll
                for (int o = 1; o < 32; o <<= 1) am = fmaxf(am, __shfl_xor(am, o));
                float qsc = 127.f / fmaxf(am, 1e-20f);
                int q = clampi8(__float2int_rn(hi_sel * qsc));
                ((unsigned char*)hint8q)[(sub << 8) + w] = (unsigned char)(q & 255);
                if (lr == 0) dqs[sub][v] = am * (1.f / 127.f);
            }
            __syncthreads();  // B1: hint8q/dqs ready

            // ---- Phase B: gh + gates + h update + FC (one phase) ----
            {
                const uint4* hq0 = ((const uint4*)hint8q) + (sub << 3);       // batch 0 slice
                const uint4* hq1 = ((const uint4*)hint8q) + 16 + (sub << 3);  // batch 1 slice
                const float* dq0 = &dqs[0][sub << 2];
                const float* dq1 = &dqs[1][sub << 2];
                float gr0 = 0.f, gz0 = 0.f, gn0 = 0.f, gr1 = 0.f, gz1 = 0.f, gn1 = 0.f;
                #pragma unroll
                for (int c2 = 0; c2 < 4; ++c2) {
                    uint4 u0a = hq0[2*c2], u0b = hq0[2*c2+1];
                    uint4 u1a = hq1[2*c2], u1b = hq1[2*c2+1];
                    const int k = c2 << 3;
                    int r0 = 0, z0 = 0, n0 = 0, r1 = 0, z1 = 0, n1 = 0;
                    r0 = sdot4(wB8[k],      u0a.x, r0); r0 = sdot4(wB8[k+1],    u0a.y, r0);
                    r0 = sdot4(wB8[k+2],    u0a.z, r0); r0 = sdot4(wB8[k+3],    u0a.w, r0);
                    r0 = sdot4(wB8[k+4],    u0b.x, r0); r0 = sdot4(wB8[k+5],    u0b.y, r0);
                    r0 = sdot4(wB8[k+6],    u0b.z, r0); r0 = sdot4(wB8[k+7],    u0b.w, r0);
                    z0 = sdot4(wB8[32+k],   u0a.x, z0); z0 = sdot4(wB8[32+k+1], u0a.y, z0);
                    z0 = sdot4(wB8[32+k+2], u0a.z, z0); z0 = sdot4(wB8[32+k+3], u0a.w, z0);
                    z0 = sdot4(wB8[32+k+4], u0b.x, z0); z0 = sdot4(wB8[32+k+5], u0b.y, z0);
                    z0 = sdot4(wB8[32+k+6], u0b.z, z0); z0 = sdot4(wB8[32+k+7], u0b.w, z0);
                    n0 = sdot4(wB8[64+k],   u0a.x, n0); n0 = sdot4(wB8[64+k+1], u0a.y, n0);
                    n0 = sdot4(wB8[64+k+2], u0a.z, n0); n0 = sdot4(wB8[64+k+3], u0a.w, n0);
                    n0 = sdot4(wB8[64+k+4], u0b.x, n0); n0 = sdot4(wB8[64+k+5], u0b.y, n0);
                    n0 = sdot4(wB8[64+k+6], u0b.z, n0); n0 = sdot4(wB8[64+k+7], u0b.w, n0);
                    r1 = sdot4(wB8[k],      u1a.x, r1); r1 = sdot4(wB8[k+1],    u1a.y, r1);
                    r1 = sdot4(wB8[k+2],    u1a.z, r1); r1 = sdot4(wB8[k+3],    u1a.w, r1);
                    r1 = sdot4(wB8[k+4],    u1b.x, r1); r1 = sdot4(wB8[k+5],    u1b.y, r1);
                    r1 = sdot4(wB8[k+6],    u1b.z, r1); r1 = sdot4(wB8[k+7],    u1b.w, r1);
                    z1 = sdot4(wB8[32+k],   u1a.x, z1); z1 = sdot4(wB8[32+k+1], u1a.y, z1);
                    z1 = sdot4(wB8[32+k+2], u1a.z, z1); z1 = sdot4(wB8[32+k+3], u1a.w, z1);
                    z1 = sdot4(wB8[32+k+4], u1b.x, z1); z1 = sdot4(wB8[32+k+5], u1b.y, z1);
                    z1 = sdot4(wB8[32+k+6], u1b.z, z1); z1 = sdot4(wB8[32+k+7], u1b.w, z1);
                    n1 = sdot4(wB8[64+k],   u1a.x, n1); n1 = sdot4(wB8[64+k+1], u1a.y, n1);
                    n1 = sdot4(wB8[64+k+2], u1a.z, n1); n1 = sdot4(wB8[64+k+3], u1a.w, n1);
                    n1 = sdot4(wB8[64+k+4], u1b.x, n1); n1 = sdot4(wB8[64+k+5], u1b.y, n1);
                    n1 = sdot4(wB8[64+k+6], u1b.z, n1); n1 = sdot4(wB8[64+k+7], u1b.w, n1);
                    const float d0 = dq0[c2], d1 = dq1[c2];
                    gr0 += (float)r0 * d0; gz0 += (float)z0 * d0; gn0 += (float)n0 * d0;
                    gr1 += (float)r1 * d1; gz1 += (float)z1 * d1; gn1 += (float)n1 * d1;
                }
                gr0 += __shfl_xor(gr0, 32); gz0 += __shfl_xor(gz0, 32); gn0 += __shfl_xor(gn0, 32);
                gr1 += __shfl_xor(gr1, 32); gz1 += __shfl_xor(gz1, 32); gn1 += __shfl_xor(gn1, 32);

                const int bsel = sub;
                float GR = (bsel ? gr1 : gr0) * bsr[0];
                float GZ = (bsel ? gz1 : gz0) * bsr[1];
                float GN = (bsel ? gn1 : gn0) * bsr[2];
                float xl = (t == 0) ? 0.f : sx[bsel][(i << 4) + col - dir];
                float xu = (i == 0) ? 0.f : sx[bsel][((i - 1) << 4) + col];
                float pu = (xl * xc0 + xu * xc1 + 1.f) * 0.5f;
                float rr_ = fsig(bA[0] * pu + bBi[0] + GR + bbh[0]);
                float zz = fsig(bA[1] * pu + bBi[1] + GZ + bbh[1]);
                float nn = ftanh_(bA[2] * pu + bBi[2] + rr_ * (GN + bbh[2]));
                float hn = (1.f - zz) * nn + zz * hi_sel;

                // h -> i8 (per-32-row scale), direct byte stores (no pack shfls)
                float am = fabsf(hn);
                #pragma unroll
                for (int o = 1; o < 32; o <<= 1) am = fmaxf(am, __shfl_xor(am, o));
                float qs = 127.f / fmaxf(am, 1e-20f);
                int q = clampi8(__float2int_rn(hn * qs));
                ((unsigned char*)h8)[(sub << 8) + w] = (unsigned char)(q & 255);
                ((unsigned char*)hp8)[(sub << 12) + (col << 8) + w] = (unsigned char)(q & 255);
                if (lr == 0) {
                    float hsc = am * (1.f / 127.f);
                    hs8[sub][v] = hsc;
                    hps8[sub][col][v] = hsc;
                }

                float s0 = hn * wfc0, s1 = hn * wfc1;
                #pragma unroll
                for (int o = 1; o < 32; o <<= 1) {
                    s0 += __shfl_xor(s0, o);
                    s1 += __shfl_xor(s1, o);
                }
                if (lr == 0) { fcp[sub][0][v] = s0; fcp[sub][1][v] = s1; }
            }
            __syncthreads();  // B2: h8/hp8/scales/fcp ready for next step
        }
    }

    // ---- final step's FC finalize + output ----
    if (tid == 0 || tid == 256) {
        const int b = tid >> 8;
        float l0 = bf0, l1 = bf1;
        #pragma unroll
        for (int vv = 0; vv < 8; ++vv) { l0 += fcp[b][0][vv]; l1 += fcp[b][1][vv]; }
        float mx = fmaxf(l0, l1);
        float lse = mx + logf(__expf(l0 - mx) + __expf(l1 - mx));
        float xcur = sx[b][15 * 16 + 0];   // last step: i=15 (odd) -> col 0
        float mm = (1.f + xcur) * 0.5f;
        lp_acc += (l0 - lse) * mm + (l1 - lse) * (1.f - mm);
        out[b0 + b] = lp_acc;
    }
}

extern "C" void kernel_launch(void* const* d_in, const int* in_sizes, int n_in,
                              void* d_out, int out_size, void* d_ws, size_t ws_size,
                              hipStream_t stream) {
    const float* x      = (const float*)d_in[0];
    const float* W_ih   = (const float*)d_in[1];
    const float* W_hh   = (const float*)d_in[2];
    const float* b_ih   = (const float*)d_in[3];
    const float* b_hh   = (const float*)d_in[4];
    const float* W_fc   = (const float*)d_in[5];
    const float* b_fc   = (const float*)d_in[6];
    const float* W_hcat = (const float*)d_in[7];
    const float* W_xcat = (const float*)d_in[8];
    float* out = (float*)d_out;
    float* ws  = (float*)d_ws;

    gru2d_prep1<<<1024, 64, 0, stream>>>(W_hh, W_hcat, ws);
    gru2d_prep2<<<323, 256, 0, stream>>>(W_ih, W_hh, b_ih, W_hcat, ws);
    gru2d_main<<<256, 512, 0, stream>>>(x, b_hh, W_fc, b_fc, W_xcat, ws, out);
}

// Round 11
// 785.672 us; speedup vs baseline: 5.5579x; 1.1447x over previous
//
#include <hip/hip_runtime.h>
#include <math.h>

#define LL 16
#define WD 256
#define G3 768

// ws layout (u32 units)
#define OFF_A8  0        // 32768 u32 : W_hcat i8 (16 uint4/thread; 2 rows x k-quarter)
#define OFF_B8  32768    // 49152 u32 : W_hh i8 (24 uint4/thread)
#define OFF_SRB 81920    // 768 f32 : per-row scale of W_hh
#define OFF_SRA 82688    // 256 f32 : per-row scale of W_hcat
#define OFF_GA  82944    // 768 f32 : W_ih[:,0]-W_ih[:,1]
#define OFF_GBI 83712    // 768 f32 : W_ih[:,1]+b_ih

__device__ __forceinline__ int sdot4(unsigned a, unsigned b, int acc) {
#if __has_builtin(__builtin_amdgcn_sdot4)
    return __builtin_amdgcn_sdot4((int)a, (int)b, acc, false);
#else
    int s = acc;
    #pragma unroll
    for (int r = 0; r < 4; ++r)
        s += (int)(signed char)(a >> (8 * r)) * (int)(signed char)(b >> (8 * r));
    return s;
#endif
}
__device__ __forceinline__ float fsig(float v) { return 1.f / (1.f + __expf(-v)); }
__device__ __forceinline__ float ftanh_(float v) {
    v = fminf(fmaxf(v, -15.f), 15.f);
    float e = __expf(-2.f * v);
    return (1.f - e) / (1.f + e);
}
__device__ __forceinline__ int clampi8(int q) {
    return q > 127 ? 127 : (q < -127 ? -127 : q);
}

// DPP-based intra-16-lane reductions (VALU pipe, not DS).
// quad_perm xor1=0xB1, xor2=0x4E; row_ror:4=0x124, row_ror:8=0x128.
template <int CTRL>
__device__ __forceinline__ float dppf(float x) {
    return __builtin_bit_cast(float, __builtin_amdgcn_update_dpp(
        0, __builtin_bit_cast(int, x), CTRL, 0xF, 0xF, true));
}
__device__ __forceinline__ float max16(float x) {
    x = fmaxf(x, dppf<0xB1>(x));
    x = fmaxf(x, dppf<0x4E>(x));
    x = fmaxf(x, dppf<0x124>(x));
    x = fmaxf(x, dppf<0x128>(x));
    return x;
}
__device__ __forceinline__ float sum16(float x) {
    x += dppf<0xB1>(x);
    x += dppf<0x4E>(x);
    x += dppf<0x124>(x);
    x += dppf<0x128>(x);
    return x;
}

// per-row max-abs scales: rows 0..767 = W_hh (256-wide), 768..1023 = W_hcat (512-wide)
__global__ __launch_bounds__(64)
void gru2d_prep1(const float* __restrict__ W_hh, const float* __restrict__ W_hcat,
                 float* __restrict__ ws) {
    int row = blockIdx.x, lane = threadIdx.x;
    float s = 0.f;
    if (row < 768) {
        for (int k = lane; k < 256; k += 64) s = fmaxf(s, fabsf(W_hh[row * 256 + k]));
    } else {
        int r = row - 768;
        for (int k = lane; k < 512; k += 64) s = fmaxf(s, fabsf(W_hcat[r * 512 + k]));
    }
    #pragma unroll
    for (int o = 32; o > 0; o >>= 1) s = fmaxf(s, __shfl_down(s, o));
    if (lane == 0) {
        float sc = (s > 0.f) ? s * (1.f / 127.f) : 1.f;
        if (row < 768) ws[OFF_SRB + row] = sc;
        else           ws[OFF_SRA + (row - 768)] = sc;
    }
}

// Main-thread role (t: v=t>>6, l=t&63, lr=l&31, sub=l>>5, q2=lr>>4):
// A8: rows rA0=v*32+(lr&15), rA1=rA0+16 of [Wh_l|Wh_u] as i8,
//     k-quarter qk=(sub<<1)|q2 -> concat-k [qk*128,+128). u32 jj<32 -> rA0 (j=jj),
//     jj>=32 -> rA1 (j=jj-32); u32 j holds k=qk*128+4j..+3.
//     Stored wsu[OFF_A8 + (g*512+t)*4+r], jj=g*4+r.
// B8: gate rows {w,256+w,512+w} (w=v*32+lr) of W_hh as i8, k in [sub*128,+128).
__global__ __launch_bounds__(256)
void gru2d_prep2(const float* __restrict__ W_ih, const float* __restrict__ W_hh,
                 const float* __restrict__ b_ih, const float* __restrict__ W_hcat,
                 float* __restrict__ ws) {
    unsigned* __restrict__ wsu = (unsigned*)ws;
    int m = blockIdx.x * 256 + threadIdx.x;
    if (m < 32768) {
        int g = m >> 11, t = (m >> 2) & 511, r = m & 3;
        int jj = g * 4 + r;
        int v = t >> 6, l = t & 63, lr = l & 31, sub = l >> 5, q2 = lr >> 4;
        int row = (v << 5) + (lr & 15) + ((jj >> 5) << 4);
        int j = jj & 31;
        int qk = (sub << 1) | q2;
        float inv = 1.f / ws[OFF_SRA + row];
        int base = row * 512 + (qk << 7) + 4 * j;
        unsigned pk = 0;
        #pragma unroll
        for (int bb = 0; bb < 4; ++bb) {
            int qv = clampi8(__float2int_rn(W_hcat[base + bb] * inv));
            pk |= ((unsigned)(qv & 255)) << (8 * bb);
        }
        wsu[OFF_A8 + m] = pk;
    } else if (m < 81920) {
        int mm = m - 32768;
        int g4 = mm >> 11, t = (mm >> 2) & 511, rr = mm & 3;
        int ql = g4 * 4 + rr;
        int gate = ql >> 5, q = ql & 31;
        int v = t >> 6, l = t & 63;
        int w = v * 32 + (l & 31), kh = l >> 5;
        int row = gate * 256 + w;
        float inv = 1.f / ws[OFF_SRB + row];
        int kb = row * 256 + kh * 128 + 4 * q;
        unsigned pk = 0;
        #pragma unroll
        for (int bb = 0; bb < 4; ++bb) {
            int qv = clampi8(__float2int_rn(W_hh[kb + bb] * inv));
            pk |= ((unsigned)(qv & 255)) << (8 * bb);
        }
        wsu[OFF_B8 + mm] = pk;
    } else if (m < 82688) {
        int e = m - 81920;
        float w0 = W_ih[2 * e], w1 = W_ih[2 * e + 1];
        ws[OFF_GA + e] = w0 - w1;
        ws[OFF_GBI + e] = w1 + b_ih[e];
    }
}

// 512 threads (2 waves/SIMD), 1 block/CU, 2 batches/block.
// 2 barriers/step. Phase A: 2 rows x k-quarter (halved DS reads), reduce via
// xor16+xor32; quant/FC reductions via DPP (VALU). Scales read as float4.
__global__ __launch_bounds__(512, 2)
void gru2d_main(const float* __restrict__ x, const float* __restrict__ b_hh,
                const float* __restrict__ W_fc, const float* __restrict__ b_fc,
                const float* __restrict__ W_xcat, const float* __restrict__ ws,
                float* __restrict__ out) {
    __shared__ __attribute__((aligned(16))) unsigned h8[2][64];       // i8 h_left
    __shared__ __attribute__((aligned(16))) unsigned hp8[2][LL][64];  // i8 prev-row h
    __shared__ __attribute__((aligned(16))) float hs8[2][8];          // h chunk scales
    __shared__ __attribute__((aligned(16))) float hps8[2][LL][8];
    __shared__ __attribute__((aligned(16))) unsigned hint8q[2][64];   // i8 hint
    __shared__ __attribute__((aligned(16))) float dqs[2][8];          // hint chunk scales
    __shared__ float fcp[2][2][8];
    __shared__ float sx[2][256];

    const int tid = threadIdx.x;
    const int v = tid >> 6, l = tid & 63;
    const int lr = l & 31, sub = l >> 5;
    const int q2 = lr >> 4;
    const int w = (v << 5) + lr;            // gates / B rows / FC row
    const int rA0 = (v << 5) + (lr & 15);   // A rows: rA0, rA0+16
    const int b0 = blockIdx.x * 2;
    const unsigned* __restrict__ wsu = (const unsigned*)ws;

    // ---- persistent i8 weights -> registers (coalesced uint4) ----
    unsigned wA8[64], wB8[96];
    #pragma unroll
    for (int g = 0; g < 16; ++g) {
        uint4 q = ((const uint4*)(wsu + OFF_A8))[g * 512 + tid];
        wA8[4*g] = q.x; wA8[4*g+1] = q.y; wA8[4*g+2] = q.z; wA8[4*g+3] = q.w;
    }
    #pragma unroll
    for (int g = 0; g < 24; ++g) {
        uint4 q = ((const uint4*)(wsu + OFF_B8))[g * 512 + tid];
        wB8[4*g] = q.x; wB8[4*g+1] = q.y; wB8[4*g+2] = q.z; wB8[4*g+3] = q.w;
    }

    const float asc0 = ws[OFF_SRA + rA0];
    const float asc1 = ws[OFF_SRA + rA0 + 16];
    float bA[3], bBi[3], bbh[3], bsr[3];
    #pragma unroll
    for (int g = 0; g < 3; ++g) {
        bA[g]  = ws[OFF_GA + (g << 8) + w];
        bBi[g] = ws[OFF_GBI + (g << 8) + w];
        bbh[g] = b_hh[(g << 8) + w];
        bsr[g] = ws[OFF_SRB + (g << 8) + w];
    }
    const float wfc0 = W_fc[w], wfc1 = W_fc[256 + w];
    sx[tid >> 8][tid & 255] = x[(b0 + (tid >> 8)) * 256 + (tid & 255)];
    {
        unsigned* hp = (unsigned*)hp8;
        #pragma unroll
        for (int g = 0; g < 4; ++g) hp[g * 512 + tid] = 0u;
        if (tid < 256) ((float*)hps8)[tid] = 0.f;
    }
    const float xc0 = W_xcat[0], xc1 = W_xcat[1];
    const float bf0 = b_fc[0], bf1 = b_fc[1];
    float lp_acc = 0.f;
    __syncthreads();

    for (int i = 0; i < LL; ++i) {
        const int odd = i & 1;
        const int dir = odd ? -1 : 1;
        const int c0g = odd ? (LL - 1) : 0;
        for (int t = 0; t < LL; ++t) {
            const int col = c0g + dir * t;
            const int sidx = (i << 4) + t;

            // per-step pins: USE+DEF each iteration -> no remat, no spill (proven)
            #pragma unroll
            for (int g = 0; g < 16; ++g)
                asm volatile("" : "+v"(wA8[4*g]), "+v"(wA8[4*g+1]), "+v"(wA8[4*g+2]), "+v"(wA8[4*g+3]));
            #pragma unroll
            for (int g = 0; g < 24; ++g)
                asm volatile("" : "+v"(wB8[4*g]), "+v"(wB8[4*g+1]), "+v"(wB8[4*g+2]), "+v"(wB8[4*g+3]));

            // ---- prev-step FC finalize (2 lanes; overlaps other waves' Phase A) ----
            if ((tid == 0 || tid == 256) && sidx > 0) {
                const int b = tid >> 8;
                int ps = sidx - 1, pi2 = ps >> 4, pt2 = ps & 15;
                int pcol = (pi2 & 1) ? (15 - pt2) : pt2;
                float l0 = bf0, l1 = bf1;
                #pragma unroll
                for (int vv = 0; vv < 8; ++vv) { l0 += fcp[b][0][vv]; l1 += fcp[b][1][vv]; }
                float mx = fmaxf(l0, l1);
                float lse = mx + logf(__expf(l0 - mx) + __expf(l1 - mx));
                float xcur = sx[b][(pi2 << 4) + pcol];
                float mm = (1.f + xcur) * 0.5f;
                float lp = (l0 - lse) * mm + (l1 - lse) * (1.f - mm);
                if (pi2 == 0 && pcol == 0) lp = 1.f - mm;
                lp_acc += lp;
            }

            // ---- Phase A: rows rA0,rA1 x both batches over k-quarter qk ----
            float hi_sel;
            {
                float f00 = 0.f, f01 = 0.f, f10 = 0.f, f11 = 0.f; // [row][batch]
                if (!(sub == 0 && t == 0)) {   // qk<2 == h_left side (0 at row start)
                    const uint4* H0;
                    const uint4* H1;
                    const float4* S0;
                    const float4* S1;
                    if (sub == 0) {
                        H0 = ((const uint4*)h8[0]) + (q2 << 3);
                        H1 = ((const uint4*)h8[1]) + (q2 << 3);
                        S0 = ((const float4*)hs8[0]) + q2;
                        S1 = ((const float4*)hs8[1]) + q2;
                    } else {
                        H0 = ((const uint4*)hp8[0][col]) + (q2 << 3);
                        H1 = ((const uint4*)hp8[1][col]) + (q2 << 3);
                        S0 = ((const float4*)hps8[0][col]) + q2;
                        S1 = ((const float4*)hps8[1][col]) + q2;
                    }
                    const float4 sc0 = *S0, sc1 = *S1;
                    #pragma unroll
                    for (int c = 0; c < 4; ++c) {
                        uint4 ua0 = H0[2*c], ub0 = H0[2*c+1];
                        uint4 ua1 = H1[2*c], ub1 = H1[2*c+1];
                        const int e = c << 3;
                        int a00 = 0, a01 = 0, a10 = 0, a11 = 0;
                        a00 = sdot4(wA8[e],   ua0.x, a00); a00 = sdot4(wA8[e+1], ua0.y, a00);
                        a00 = sdot4(wA8[e+2], ua0.z, a00); a00 = sdot4(wA8[e+3], ua0.w, a00);
                        a00 = sdot4(wA8[e+4], ub0.x, a00); a00 = sdot4(wA8[e+5], ub0.y, a00);
                        a00 = sdot4(wA8[e+6], ub0.z, a00); a00 = sdot4(wA8[e+7], ub0.w, a00);
                        a10 = sdot4(wA8[32+e],   ua0.x, a10); a10 = sdot4(wA8[32+e+1], ua0.y, a10);
                        a10 = sdot4(wA8[32+e+2], ua0.z, a10); a10 = sdot4(wA8[32+e+3], ua0.w, a10);
                        a10 = sdot4(wA8[32+e+4], ub0.x, a10); a10 = sdot4(wA8[32+e+5], ub0.y, a10);
                        a10 = sdot4(wA8[32+e+6], ub0.z, a10); a10 = sdot4(wA8[32+e+7], ub0.w, a10);
                        a01 = sdot4(wA8[e],   ua1.x, a01); a01 = sdot4(wA8[e+1], ua1.y, a01);
                        a01 = sdot4(wA8[e+2], ua1.z, a01); a01 = sdot4(wA8[e+3], ua1.w, a01);
                        a01 = sdot4(wA8[e+4], ub1.x, a01); a01 = sdot4(wA8[e+5], ub1.y, a01);
                        a01 = sdot4(wA8[e+6], ub1.z, a01); a01 = sdot4(wA8[e+7], ub1.w, a01);
                        a11 = sdot4(wA8[32+e],   ua1.x, a11); a11 = sdot4(wA8[32+e+1], ua1.y, a11);
                        a11 = sdot4(wA8[32+e+2], ua1.z, a11); a11 = sdot4(wA8[32+e+3], ua1.w, a11);
                        a11 = sdot4(wA8[32+e+4], ub1.x, a11); a11 = sdot4(wA8[32+e+5], ub1.y, a11);
                        a11 = sdot4(wA8[32+e+6], ub1.z, a11); a11 = sdot4(wA8[32+e+7], ub1.w, a11);
                        const float s0c = ((const float*)&sc0)[c];
                        const float s1c = ((const float*)&sc1)[c];
                        f00 += (float)a00 * s0c; f01 += (float)a01 * s1c;
                        f10 += (float)a10 * s0c; f11 += (float)a11 * s1c;
                    }
                    f00 *= asc0; f01 *= asc0;
                    f10 *= asc1; f11 *= asc1;
                }
                // cross-k reduce: xor16 (q2) + xor32 (sub)
                f00 += __shfl_xor(f00, 16); f00 += __shfl_xor(f00, 32);
                f01 += __shfl_xor(f01, 16); f01 += __shfl_xor(f01, 32);
                f10 += __shfl_xor(f10, 16); f10 += __shfl_xor(f10, 32);
                f11 += __shfl_xor(f11, 16); f11 += __shfl_xor(f11, 32);

                // gate-select stays in-register: row w = rA0 + 16*q2, batch = sub
                hi_sel = q2 ? (sub ? f11 : f10) : (sub ? f01 : f00);

                // quant scale: max over 32 rows (chunk v) for batch=sub, DPP-only
                float m_ = fmaxf(fabsf(sub ? f01 : f00), fabsf(sub ? f11 : f10));
                m_ = max16(m_);
                float qsc = 127.f / fmaxf(m_, 1e-20f);
                int q = clampi8(__float2int_rn(hi_sel * qsc));
                ((unsigned char*)hint8q)[(sub << 8) + w] = (unsigned char)(q & 255);
                if (lr == 0) dqs[sub][v] = m_ * (1.f / 127.f);
            }
            __syncthreads();  // B1: hint8q/dqs ready

            // ---- Phase B: gh + gates + h update + FC ----
            {
                const uint4* hq0 = ((const uint4*)hint8q) + (sub << 3);
                const uint4* hq1 = ((const uint4*)hint8q) + 16 + (sub << 3);
                const float4 dq0v = ((const float4*)dqs[0])[sub];
                const float4 dq1v = ((const float4*)dqs[1])[sub];
                float gr0 = 0.f, gz0 = 0.f, gn0 = 0.f, gr1 = 0.f, gz1 = 0.f, gn1 = 0.f;
                #pragma unroll
                for (int c2 = 0; c2 < 4; ++c2) {
                    uint4 u0a = hq0[2*c2], u0b = hq0[2*c2+1];
                    uint4 u1a = hq1[2*c2], u1b = hq1[2*c2+1];
                    const int k = c2 << 3;
                    int r0 = 0, z0 = 0, n0 = 0, r1 = 0, z1 = 0, n1 = 0;
                    r0 = sdot4(wB8[k],      u0a.x, r0); r0 = sdot4(wB8[k+1],    u0a.y, r0);
                    r0 = sdot4(wB8[k+2],    u0a.z, r0); r0 = sdot4(wB8[k+3],    u0a.w, r0);
                    r0 = sdot4(wB8[k+4],    u0b.x, r0); r0 = sdot4(wB8[k+5],    u0b.y, r0);
                    r0 = sdot4(wB8[k+6],    u0b.z, r0); r0 = sdot4(wB8[k+7],    u0b.w, r0);
                    z0 = sdot4(wB8[32+k],   u0a.x, z0); z0 = sdot4(wB8[32+k+1], u0a.y, z0);
                    z0 = sdot4(wB8[32+k+2], u0a.z, z0); z0 = sdot4(wB8[32+k+3], u0a.w, z0);
                    z0 = sdot4(wB8[32+k+4], u0b.x, z0); z0 = sdot4(wB8[32+k+5], u0b.y, z0);
                    z0 = sdot4(wB8[32+k+6], u0b.z, z0); z0 = sdot4(wB8[32+k+7], u0b.w, z0);
                    n0 = sdot4(wB8[64+k],   u0a.x, n0); n0 = sdot4(wB8[64+k+1], u0a.y, n0);
                    n0 = sdot4(wB8[64+k+2], u0a.z, n0); n0 = sdot4(wB8[64+k+3], u0a.w, n0);
                    n0 = sdot4(wB8[64+k+4], u0b.x, n0); n0 = sdot4(wB8[64+k+5], u0b.y, n0);
                    n0 = sdot4(wB8[64+k+6], u0b.z, n0); n0 = sdot4(wB8[64+k+7], u0b.w, n0);
                    r1 = sdot4(wB8[k],      u1a.x, r1); r1 = sdot4(wB8[k+1],    u1a.y, r1);
                    r1 = sdot4(wB8[k+2],    u1a.z, r1); r1 = sdot4(wB8[k+3],    u1a.w, r1);
                    r1 = sdot4(wB8[k+4],    u1b.x, r1); r1 = sdot4(wB8[k+5],    u1b.y, r1);
                    r1 = sdot4(wB8[k+6],    u1b.z, r1); r1 = sdot4(wB8[k+7],    u1b.w, r1);
                    z1 = sdot4(wB8[32+k],   u1a.x, z1); z1 = sdot4(wB8[32+k+1], u1a.y, z1);
                    z1 = sdot4(wB8[32+k+2], u1a.z, z1); z1 = sdot4(wB8[32+k+3], u1a.w, z1);
                    z1 = sdot4(wB8[32+k+4], u1b.x, z1); z1 = sdot4(wB8[32+k+5], u1b.y, z1);
                    z1 = sdot4(wB8[32+k+6], u1b.z, z1); z1 = sdot4(wB8[32+k+7], u1b.w, z1);
                    n1 = sdot4(wB8[64+k],   u1a.x, n1); n1 = sdot4(wB8[64+k+1], u1a.y, n1);
                    n1 = sdot4(wB8[64+k+2], u1a.z, n1); n1 = sdot4(wB8[64+k+3], u1a.w, n1);
                    n1 = sdot4(wB8[64+k+4], u1b.x, n1); n1 = sdot4(wB8[64+k+5], u1b.y, n1);
                    n1 = sdot4(wB8[64+k+6], u1b.z, n1); n1 = sdot4(wB8[64+k+7], u1b.w, n1);
                    const float d0 = ((const float*)&dq0v)[c2];
                    const float d1 = ((const float*)&dq1v)[c2];
                    gr0 += (float)r0 * d0; gz0 += (float)z0 * d0; gn0 += (float)n0 * d0;
                    gr1 += (float)r1 * d1; gz1 += (float)z1 * d1; gn1 += (float)n1 * d1;
                }
                gr0 += __shfl_xor(gr0, 32); gz0 += __shfl_xor(gz0, 32); gn0 += __shfl_xor(gn0, 32);
                gr1 += __shfl_xor(gr1, 32); gz1 += __shfl_xor(gz1, 32); gn1 += __shfl_xor(gn1, 32);

                const int bsel = sub;
                float GR = (bsel ? gr1 : gr0) * bsr[0];
                float GZ = (bsel ? gz1 : gz0) * bsr[1];
                float GN = (bsel ? gn1 : gn0) * bsr[2];
                float xl = (t == 0) ? 0.f : sx[bsel][(i << 4) + col - dir];
                float xu = (i == 0) ? 0.f : sx[bsel][((i - 1) << 4) + col];
                float pu = (xl * xc0 + xu * xc1 + 1.f) * 0.5f;
                float rr_ = fsig(bA[0] * pu + bBi[0] + GR + bbh[0]);
                float zz = fsig(bA[1] * pu + bBi[1] + GZ + bbh[1]);
                float nn = ftanh_(bA[2] * pu + bBi[2] + rr_ * (GN + bbh[2]));
                float hn = (1.f - zz) * nn + zz * hi_sel;

                // h -> i8: max over 32 rows via 4 DPP + 1 shfl(16)
                float am = max16(fabsf(hn));
                am = fmaxf(am, __shfl_xor(am, 16));
                float qs = 127.f / fmaxf(am, 1e-20f);
                int q = clampi8(__float2int_rn(hn * qs));
                ((unsigned char*)h8)[(sub << 8) + w] = (unsigned char)(q & 255);
                ((unsigned char*)hp8)[(sub << 12) + (col << 8) + w] = (unsigned char)(q & 255);
                if (lr == 0) {
                    float hsc = am * (1.f / 127.f);
                    hs8[sub][v] = hsc;
                    hps8[sub][col][v] = hsc;
                }

                // FC partial: sum over 32 lanes via 4 DPP + 1 shfl(16) each
                float s0 = hn * wfc0, s1 = hn * wfc1;
                s0 = sum16(s0); s0 += __shfl_xor(s0, 16);
                s1 = sum16(s1); s1 += __shfl_xor(s1, 16);
                if (lr == 0) { fcp[sub][0][v] = s0; fcp[sub][1][v] = s1; }
            }
            __syncthreads();  // B2: h8/hp8/scales/fcp ready for next step
        }
    }

    // ---- final step's FC finalize + output ----
    if (tid == 0 || tid == 256) {
        const int b = tid >> 8;
        float l0 = bf0, l1 = bf1;
        #pragma unroll
        for (int vv = 0; vv < 8; ++vv) { l0 += fcp[b][0][vv]; l1 += fcp[b][1][vv]; }
        float mx = fmaxf(l0, l1);
        float lse = mx + logf(__expf(l0 - mx) + __expf(l1 - mx));
        float xcur = sx[b][15 * 16 + 0];   // last step: i=15 (odd) -> col 0
        float mm = (1.f + xcur) * 0.5f;
        lp_acc += (l0 - lse) * mm + (l1 - lse) * (1.f - mm);
        out[b0 + b] = lp_acc;
    }
}

extern "C" void kernel_launch(void* const* d_in, const int* in_sizes, int n_in,
                              void* d_out, int out_size, void* d_ws, size_t ws_size,
                              hipStream_t stream) {
    const float* x      = (const float*)d_in[0];
    const float* W_ih   = (const float*)d_in[1];
    const float* W_hh   = (const float*)d_in[2];
    const float* b_ih   = (const float*)d_in[3];
    const float* b_hh   = (const float*)d_in[4];
    const float* W_fc   = (const float*)d_in[5];
    const float* b_fc   = (const float*)d_in[6];
    const float* W_hcat = (const float*)d_in[7];
    const float* W_xcat = (const float*)d_in[8];
    float* out = (float*)d_out;
    float* ws  = (float*)d_ws;

    gru2d_prep1<<<1024, 64, 0, stream>>>(W_hh, W_hcat, ws);
    gru2d_prep2<<<323, 256, 0, stream>>>(W_ih, W_hh, b_ih, W_hcat, ws);
    gru2d_main<<<256, 512, 0, stream>>>(x, b_hh, W_fc, b_fc, W_xcat, ws, out);
}